// Round 1
// baseline (1310.294 us; speedup 1.0000x reference)
//
#include <hip/hip_runtime.h>
#include <math.h>

#define NN 50000
#define EE 800000
#define ET (NN + EE)   // 850000 edges incl. self-loops
#define GG 64

__device__ __forceinline__ float lrelu(float x) { return x > 0.f ? x : 0.2f * x; }

// ---------------- CSR build ----------------
__global__ void k_count(const int* __restrict__ ei, int* __restrict__ deg) {
  int e = blockIdx.x * 256 + threadIdx.x;
  if (e >= ET) return;
  int dst = (e < EE) ? ei[EE + e] : (e - EE);
  atomicAdd(&deg[dst], 1);
}

__global__ void k_scan(const int* __restrict__ deg, int* __restrict__ offs) {
  __shared__ int s[1024];
  __shared__ int carry_s;
  if (threadIdx.x == 0) carry_s = 0;
  __syncthreads();
  for (int base = 0; base < NN; base += 1024) {
    int i = base + threadIdx.x;
    int v = (i < NN) ? deg[i] : 0;
    s[threadIdx.x] = v;
    __syncthreads();
    for (int off = 1; off < 1024; off <<= 1) {
      int t = (threadIdx.x >= off) ? s[threadIdx.x - off] : 0;
      __syncthreads();
      s[threadIdx.x] += t;
      __syncthreads();
    }
    int c = carry_s;
    if (i < NN) offs[i] = c + s[threadIdx.x] - v;  // exclusive
    int tot = s[1023];
    __syncthreads();
    if (threadIdx.x == 0) carry_s = c + tot;
    __syncthreads();
  }
  if (threadIdx.x == 0) offs[NN] = carry_s;
}

__global__ void k_fill(const int* __restrict__ ei, const int* __restrict__ offs,
                       int* __restrict__ cursor, int* __restrict__ csr) {
  int e = blockIdx.x * 256 + threadIdx.x;
  if (e >= ET) return;
  int src, dst;
  if (e < EE) { src = ei[e]; dst = ei[EE + e]; } else { src = dst = e - EE; }
  int slot = offs[dst] + atomicAdd(&cursor[dst], 1);
  csr[slot] = src;
}

// ---------------- h = x@W  +  al_s/al_d (fused) ----------------
// block: 256 threads -> 8 rows x 256 cols. Wave w == head w for the al reduce.
template <int K>
__global__ void k_lin(const float* __restrict__ xin, const float* __restrict__ W,
                      const float* __restrict__ a_s, const float* __restrict__ a_d,
                      float* __restrict__ h, float* __restrict__ al) {
  __shared__ float xs[8 * K];
  const int c = threadIdx.x;
  const int row0 = blockIdx.x * 8;
  for (int i = c; i < 8 * K; i += 256) xs[i] = xin[row0 * K + i];
  __syncthreads();
  float acc[8] = {};
  for (int k = 0; k < K; ++k) {
    float w = W[k * 256 + c];
#pragma unroll
    for (int r = 0; r < 8; ++r) acc[r] = fmaf(xs[r * K + k], w, acc[r]);
  }
  const float asc = a_s[c], adc = a_d[c];
#pragma unroll
  for (int r = 0; r < 8; ++r) h[(row0 + r) * 256 + c] = acc[r];
  float ps[8], pd[8];
#pragma unroll
  for (int r = 0; r < 8; ++r) { ps[r] = acc[r] * asc; pd[r] = acc[r] * adc; }
#pragma unroll
  for (int off = 32; off >= 1; off >>= 1) {
#pragma unroll
    for (int r = 0; r < 8; ++r) {
      ps[r] += __shfl_xor(ps[r], off, 64);
      pd[r] += __shfl_xor(pd[r], off, 64);
    }
  }
  if ((c & 63) == 0) {
    int head = c >> 6;
#pragma unroll
    for (int r = 0; r < 8; ++r) {
      al[(row0 + r) * 8 + head] = ps[r];
      al[(row0 + r) * 8 + 4 + head] = pd[r];
    }
  }
}

// ---------------- per-dst softmax + aggregate (wave per node, no atomics) --------
__global__ void k_agg(const float* __restrict__ h, const float* __restrict__ al,
                      const int* __restrict__ offs, const int* __restrict__ csr,
                      const float* __restrict__ bias, float* __restrict__ out,
                      const int do_relu) {
  const int lane = threadIdx.x & 63;
  const int n = blockIdx.x * 4 + (threadIdx.x >> 6);
  const int head = lane >> 4;
  const int start = offs[n], end = offs[n + 1];
  const float4 ald4 = *(const float4*)&al[n * 8 + 4];
  float m0 = -1e30f, m1 = -1e30f, m2 = -1e30f, m3 = -1e30f;
  for (int i = start + lane; i < end; i += 64) {
    int s = csr[i];
    const float4 as4 = *(const float4*)&al[s * 8];
    m0 = fmaxf(m0, lrelu(as4.x + ald4.x));
    m1 = fmaxf(m1, lrelu(as4.y + ald4.y));
    m2 = fmaxf(m2, lrelu(as4.z + ald4.z));
    m3 = fmaxf(m3, lrelu(as4.w + ald4.w));
  }
#pragma unroll
  for (int off = 32; off >= 1; off >>= 1) {
    m0 = fmaxf(m0, __shfl_xor(m0, off, 64));
    m1 = fmaxf(m1, __shfl_xor(m1, off, 64));
    m2 = fmaxf(m2, __shfl_xor(m2, off, 64));
    m3 = fmaxf(m3, __shfl_xor(m3, off, 64));
  }
  const float m_my = (head == 0) ? m0 : (head == 1) ? m1 : (head == 2) ? m2 : m3;
  const float ald_my = (head == 0) ? ald4.x : (head == 1) ? ald4.y : (head == 2) ? ald4.z : ald4.w;
  float ax = 0.f, ay = 0.f, az = 0.f, aw = 0.f, denom = 0.f;
  for (int i = start; i < end; ++i) {
    int s = csr[i];
    float p = __expf(lrelu(al[s * 8 + head] + ald_my) - m_my);
    denom += p;
    const float4 hv = *(const float4*)&h[s * 256 + lane * 4];
    ax = fmaf(p, hv.x, ax);
    ay = fmaf(p, hv.y, ay);
    az = fmaf(p, hv.z, az);
    aw = fmaf(p, hv.w, aw);
  }
  const float inv = 0.25f / denom;  // alpha normalize + head mean
  ax *= inv; ay *= inv; az *= inv; aw *= inv;
  ax += __shfl_xor(ax, 16, 64); ax += __shfl_xor(ax, 32, 64);
  ay += __shfl_xor(ay, 16, 64); ay += __shfl_xor(ay, 32, 64);
  az += __shfl_xor(az, 16, 64); az += __shfl_xor(az, 32, 64);
  aw += __shfl_xor(aw, 16, 64); aw += __shfl_xor(aw, 32, 64);
  if (lane < 16) {
    const float4 b4 = *(const float4*)&bias[lane * 4];
    float4 o;
    o.x = ax + b4.x; o.y = ay + b4.y; o.z = az + b4.z; o.w = aw + b4.w;
    if (do_relu) {
      o.x = fmaxf(o.x, 0.f); o.y = fmaxf(o.y, 0.f);
      o.z = fmaxf(o.z, 0.f); o.w = fmaxf(o.w, 0.f);
    }
    *(float4*)&out[n * 64 + lane * 4] = o;
  }
}

// ---------------- node MLP heads + pooling (wave per node) ----------------
__global__ void k_heads(const float* __restrict__ emb, const int* __restrict__ batch,
                        const float* __restrict__ aw1, const float* __restrict__ ab1,
                        const float* __restrict__ aw2, const float* __restrict__ ab2,
                        const float* __restrict__ rw1, const float* __restrict__ rb1,
                        const float* __restrict__ rw2, const float* __restrict__ rb2,
                        const float* __restrict__ cw1, const float* __restrict__ cb1,
                        const float* __restrict__ cw2, const float* __restrict__ cb2,
                        float* __restrict__ anomaly, float* __restrict__ risk,
                        float* __restrict__ resource, float* __restrict__ pooled,
                        float* __restrict__ cnt) {
  const int lane = threadIdx.x & 63;
  const int n = blockIdx.x * 4 + (threadIdx.x >> 6);
  const float e = emb[n * 64 + lane];
  const int g = batch[n];
  atomicAdd(&pooled[g * 64 + lane], e);
  if (lane == 0) atomicAdd(&cnt[g], 1.0f);
  const int k = lane & 31;
  const bool hi = lane >= 32;
  const float* w1 = hi ? rw1 : aw1;
  const float* b1 = hi ? rb1 : ab1;
  float hA = b1[k];
  float hC = cb1[k];
  for (int cc = 0; cc < 64; ++cc) {
    float bc = __shfl(e, cc, 64);
    hA = fmaf(bc, w1[cc * 32 + k], hA);
    hC = fmaf(bc, cw1[cc * 32 + k], hC);
  }
  hA = fmaxf(hA, 0.f);
  hC = fmaxf(hC, 0.f);
  const float* w2 = hi ? rw2 : aw2;
  float pA = hA * w2[k];
  float pR[5];
#pragma unroll
  for (int j = 0; j < 5; ++j) pR[j] = hC * cw2[k * 5 + j];
#pragma unroll
  for (int off = 1; off <= 16; off <<= 1) {
    pA += __shfl_xor(pA, off, 64);
#pragma unroll
    for (int j = 0; j < 5; ++j) pR[j] += __shfl_xor(pR[j], off, 64);
  }
  if (lane == 0) {
    anomaly[n] = 1.f / (1.f + __expf(-(pA + ab2[0])));
#pragma unroll
    for (int j = 0; j < 5; ++j) resource[n * 5 + j] = pR[j] + cb2[j];
  }
  if (lane == 32) risk[n] = 1.f / (1.f + __expf(-(pA + rb2[0])));
}

// ---------------- graph MLP ----------------
__global__ void k_graph(const float* __restrict__ pooled, const float* __restrict__ cnt,
                        const float* __restrict__ gw1, const float* __restrict__ gb1,
                        const float* __restrict__ gw2, const float* __restrict__ gb2,
                        float* __restrict__ logits) {
  const int g = blockIdx.x;
  const int k = threadIdx.x;  // 0..31
  const float inv = 1.f / fmaxf(cnt[g], 1.f);
  float hG = gb1[k];
  for (int cc = 0; cc < 64; ++cc) hG = fmaf(pooled[g * 64 + cc] * inv, gw1[cc * 32 + k], hG);
  hG = fmaxf(hG, 0.f);
  float p[4];
#pragma unroll
  for (int j = 0; j < 4; ++j) p[j] = hG * gw2[k * 4 + j];
#pragma unroll
  for (int off = 1; off <= 16; off <<= 1) {
#pragma unroll
    for (int j = 0; j < 4; ++j) p[j] += __shfl_xor(p[j], off, 64);
  }
  if (k == 0) {
#pragma unroll
    for (int j = 0; j < 4; ++j) logits[g * 4 + j] = p[j] + gb2[j];
  }
}

extern "C" void kernel_launch(void* const* d_in, const int* in_sizes, int n_in,
                              void* d_out, int out_size, void* d_ws, size_t ws_size,
                              hipStream_t stream) {
  const float* x = (const float*)d_in[0];
  const int* ei = (const int*)d_in[1];
  const int* batch = (const int*)d_in[2];
  const float* W1 = (const float*)d_in[3];
  const float* as1 = (const float*)d_in[4];
  const float* ad1 = (const float*)d_in[5];
  const float* b1 = (const float*)d_in[6];
  const float* W2 = (const float*)d_in[7];
  const float* as2 = (const float*)d_in[8];
  const float* ad2 = (const float*)d_in[9];
  const float* b2 = (const float*)d_in[10];
  const float* W3 = (const float*)d_in[11];
  const float* as3 = (const float*)d_in[12];
  const float* ad3 = (const float*)d_in[13];
  const float* b3 = (const float*)d_in[14];
  const float* aw1 = (const float*)d_in[15];
  const float* ab1 = (const float*)d_in[16];
  const float* aw2 = (const float*)d_in[17];
  const float* ab2 = (const float*)d_in[18];
  const float* rw1 = (const float*)d_in[19];
  const float* rb1 = (const float*)d_in[20];
  const float* rw2 = (const float*)d_in[21];
  const float* rb2 = (const float*)d_in[22];
  const float* cw1 = (const float*)d_in[23];
  const float* cb1 = (const float*)d_in[24];
  const float* cw2 = (const float*)d_in[25];
  const float* cb2 = (const float*)d_in[26];
  const float* gw1 = (const float*)d_in[27];
  const float* gb1 = (const float*)d_in[28];
  const float* gw2 = (const float*)d_in[29];
  const float* gb2 = (const float*)d_in[30];

  float* out = (float*)d_out;
  float* emb = out;                       // [N,64]
  float* anomaly = out + NN * 64;         // [N]
  float* risk = anomaly + NN;             // [N]
  float* resource = risk + NN;            // [N,5]
  float* logits = resource + NN * 5;      // [G,4]

  char* ws = (char*)d_ws;
  int* deg = (int*)ws;            ws += (size_t)NN * 4;
  int* cursor = (int*)ws;         ws += (size_t)NN * 4;
  float* pooled = (float*)ws;     ws += (size_t)GG * 64 * 4;
  float* cnt = (float*)ws;        ws += (size_t)GG * 4;
  size_t zbytes = (size_t)(NN * 2 + GG * 64 + GG) * 4;
  int* offs = (int*)ws;           ws += (size_t)(NN + 4) * 4;  // padded to 16B
  int* csr = (int*)ws;            ws += (size_t)ET * 4;
  float* h = (float*)ws;          ws += (size_t)NN * 256 * 4;
  float* al = (float*)ws;         ws += (size_t)NN * 8 * 4;
  float* xbuf = (float*)ws;       ws += (size_t)NN * 64 * 4;

  hipMemsetAsync(d_ws, 0, zbytes, stream);
  k_count<<<(ET + 255) / 256, 256, 0, stream>>>(ei, deg);
  k_scan<<<1, 1024, 0, stream>>>(deg, offs);
  k_fill<<<(ET + 255) / 256, 256, 0, stream>>>(ei, offs, cursor, csr);

  // layer 1
  k_lin<128><<<NN / 8, 256, 0, stream>>>(x, W1, as1, ad1, h, al);
  k_agg<<<NN / 4, 256, 0, stream>>>(h, al, offs, csr, b1, xbuf, 1);
  // layer 2
  k_lin<64><<<NN / 8, 256, 0, stream>>>(xbuf, W2, as2, ad2, h, al);
  k_agg<<<NN / 4, 256, 0, stream>>>(h, al, offs, csr, b2, xbuf, 1);
  // layer 3
  k_lin<64><<<NN / 8, 256, 0, stream>>>(xbuf, W3, as3, ad3, h, al);
  k_agg<<<NN / 4, 256, 0, stream>>>(h, al, offs, csr, b3, emb, 0);

  k_heads<<<NN / 4, 256, 0, stream>>>(emb, batch, aw1, ab1, aw2, ab2, rw1, rb1, rw2, rb2,
                                      cw1, cb1, cw2, cb2, anomaly, risk, resource, pooled, cnt);
  k_graph<<<GG, 32, 0, stream>>>(pooled, cnt, gw1, gb1, gw2, gb2, logits);
}

// Round 2
// 1046.901 us; speedup vs baseline: 1.2516x; 1.2516x over previous
//
#include <hip/hip_runtime.h>
#include <math.h>

#define NN 50000
#define EE 800000
#define ET (NN + EE)   // 850000 edges incl. self-loops
#define GG 64

__device__ __forceinline__ float lrelu(float x) { return x > 0.f ? x : 0.2f * x; }

// ---------------- CSR build ----------------
__global__ void k_count(const int* __restrict__ ei, int* __restrict__ deg) {
  int e = blockIdx.x * 256 + threadIdx.x;
  if (e >= ET) return;
  int dst = (e < EE) ? ei[EE + e] : (e - EE);
  atomicAdd(&deg[dst], 1);
}

__global__ void k_scan(const int* __restrict__ deg, int* __restrict__ offs) {
  __shared__ int s[1024];
  __shared__ int carry_s;
  if (threadIdx.x == 0) carry_s = 0;
  __syncthreads();
  for (int base = 0; base < NN; base += 1024) {
    int i = base + threadIdx.x;
    int v = (i < NN) ? deg[i] : 0;
    s[threadIdx.x] = v;
    __syncthreads();
    for (int off = 1; off < 1024; off <<= 1) {
      int t = (threadIdx.x >= off) ? s[threadIdx.x - off] : 0;
      __syncthreads();
      s[threadIdx.x] += t;
      __syncthreads();
    }
    int c = carry_s;
    if (i < NN) offs[i] = c + s[threadIdx.x] - v;  // exclusive
    int tot = s[1023];
    __syncthreads();
    if (threadIdx.x == 0) carry_s = c + tot;
    __syncthreads();
  }
  if (threadIdx.x == 0) offs[NN] = carry_s;
}

__global__ void k_fill(const int* __restrict__ ei, const int* __restrict__ offs,
                       int* __restrict__ cursor, int* __restrict__ csr) {
  int e = blockIdx.x * 256 + threadIdx.x;
  if (e >= ET) return;
  int src, dst;
  if (e < EE) { src = ei[e]; dst = ei[EE + e]; } else { src = dst = e - EE; }
  int slot = offs[dst] + atomicAdd(&cursor[dst], 1);
  csr[slot] = src;
}

// ---------------- h = x@W  +  al_s/al_d (fused) ----------------
// block: 256 threads -> 8 rows x 256 cols. Wave w == head w for the al reduce.
template <int K>
__global__ void k_lin(const float* __restrict__ xin, const float* __restrict__ W,
                      const float* __restrict__ a_s, const float* __restrict__ a_d,
                      float* __restrict__ h, float* __restrict__ al) {
  __shared__ float xs[8 * K];
  const int c = threadIdx.x;
  const int row0 = blockIdx.x * 8;
  for (int i = c; i < 8 * K; i += 256) xs[i] = xin[row0 * K + i];
  __syncthreads();
  float acc[8] = {};
  for (int k = 0; k < K; ++k) {
    float w = W[k * 256 + c];
#pragma unroll
    for (int r = 0; r < 8; ++r) acc[r] = fmaf(xs[r * K + k], w, acc[r]);
  }
  const float asc = a_s[c], adc = a_d[c];
#pragma unroll
  for (int r = 0; r < 8; ++r) h[(row0 + r) * 256 + c] = acc[r];
  float ps[8], pd[8];
#pragma unroll
  for (int r = 0; r < 8; ++r) { ps[r] = acc[r] * asc; pd[r] = acc[r] * adc; }
#pragma unroll
  for (int off = 32; off >= 1; off >>= 1) {
#pragma unroll
    for (int r = 0; r < 8; ++r) {
      ps[r] += __shfl_xor(ps[r], off, 64);
      pd[r] += __shfl_xor(pd[r], off, 64);
    }
  }
  if ((c & 63) == 0) {
    int head = c >> 6;
#pragma unroll
    for (int r = 0; r < 8; ++r) {
      al[(row0 + r) * 8 + head] = ps[r];
      al[(row0 + r) * 8 + 4 + head] = pd[r];
    }
  }
}

// ---------------- per-dst softmax + aggregate (wave per node, no atomics) --------
__global__ void k_agg(const float* __restrict__ h, const float* __restrict__ al,
                      const int* __restrict__ offs, const int* __restrict__ csr,
                      const float* __restrict__ bias, float* __restrict__ out,
                      const int do_relu) {
  const int lane = threadIdx.x & 63;
  const int n = blockIdx.x * 4 + (threadIdx.x >> 6);
  const int head = lane >> 4;
  const int start = offs[n], end = offs[n + 1];
  const float4 ald4 = *(const float4*)&al[n * 8 + 4];
  float m0 = -1e30f, m1 = -1e30f, m2 = -1e30f, m3 = -1e30f;
  for (int i = start + lane; i < end; i += 64) {
    int s = csr[i];
    const float4 as4 = *(const float4*)&al[s * 8];
    m0 = fmaxf(m0, lrelu(as4.x + ald4.x));
    m1 = fmaxf(m1, lrelu(as4.y + ald4.y));
    m2 = fmaxf(m2, lrelu(as4.z + ald4.z));
    m3 = fmaxf(m3, lrelu(as4.w + ald4.w));
  }
#pragma unroll
  for (int off = 32; off >= 1; off >>= 1) {
    m0 = fmaxf(m0, __shfl_xor(m0, off, 64));
    m1 = fmaxf(m1, __shfl_xor(m1, off, 64));
    m2 = fmaxf(m2, __shfl_xor(m2, off, 64));
    m3 = fmaxf(m3, __shfl_xor(m3, off, 64));
  }
  const float m_my = (head == 0) ? m0 : (head == 1) ? m1 : (head == 2) ? m2 : m3;
  const float ald_my = (head == 0) ? ald4.x : (head == 1) ? ald4.y : (head == 2) ? ald4.z : ald4.w;
  float ax = 0.f, ay = 0.f, az = 0.f, aw = 0.f, denom = 0.f;
  for (int i = start; i < end; ++i) {
    int s = csr[i];
    float p = __expf(lrelu(al[s * 8 + head] + ald_my) - m_my);
    denom += p;
    const float4 hv = *(const float4*)&h[s * 256 + lane * 4];
    ax = fmaf(p, hv.x, ax);
    ay = fmaf(p, hv.y, ay);
    az = fmaf(p, hv.z, az);
    aw = fmaf(p, hv.w, aw);
  }
  const float inv = 0.25f / denom;  // alpha normalize + head mean
  ax *= inv; ay *= inv; az *= inv; aw *= inv;
  ax += __shfl_xor(ax, 16, 64); ax += __shfl_xor(ax, 32, 64);
  ay += __shfl_xor(ay, 16, 64); ay += __shfl_xor(ay, 32, 64);
  az += __shfl_xor(az, 16, 64); az += __shfl_xor(az, 32, 64);
  aw += __shfl_xor(aw, 16, 64); aw += __shfl_xor(aw, 32, 64);
  if (lane < 16) {
    const float4 b4 = *(const float4*)&bias[lane * 4];
    float4 o;
    o.x = ax + b4.x; o.y = ay + b4.y; o.z = az + b4.z; o.w = aw + b4.w;
    if (do_relu) {
      o.x = fmaxf(o.x, 0.f); o.y = fmaxf(o.y, 0.f);
      o.z = fmaxf(o.z, 0.f); o.w = fmaxf(o.w, 0.f);
    }
    *(float4*)&out[n * 64 + lane * 4] = o;
  }
}

// ---------------- node MLP heads (wave per node; no atomics) ----------------
__global__ void k_heads(const float* __restrict__ emb,
                        const float* __restrict__ aw1, const float* __restrict__ ab1,
                        const float* __restrict__ aw2, const float* __restrict__ ab2,
                        const float* __restrict__ rw1, const float* __restrict__ rb1,
                        const float* __restrict__ rw2, const float* __restrict__ rb2,
                        const float* __restrict__ cw1, const float* __restrict__ cb1,
                        const float* __restrict__ cw2, const float* __restrict__ cb2,
                        float* __restrict__ anomaly, float* __restrict__ risk,
                        float* __restrict__ resource) {
  const int lane = threadIdx.x & 63;
  const int n = blockIdx.x * 4 + (threadIdx.x >> 6);
  const float e = emb[n * 64 + lane];
  const int k = lane & 31;
  const bool hi = lane >= 32;
  const float* w1 = hi ? rw1 : aw1;
  const float* b1 = hi ? rb1 : ab1;
  float hA = b1[k];
  float hC = cb1[k];
  for (int cc = 0; cc < 64; ++cc) {
    float bc = __shfl(e, cc, 64);
    hA = fmaf(bc, w1[cc * 32 + k], hA);
    hC = fmaf(bc, cw1[cc * 32 + k], hC);
  }
  hA = fmaxf(hA, 0.f);
  hC = fmaxf(hC, 0.f);
  const float* w2 = hi ? rw2 : aw2;
  float pA = hA * w2[k];
  float pR[5];
#pragma unroll
  for (int j = 0; j < 5; ++j) pR[j] = hC * cw2[k * 5 + j];
#pragma unroll
  for (int off = 1; off <= 16; off <<= 1) {
    pA += __shfl_xor(pA, off, 64);
#pragma unroll
    for (int j = 0; j < 5; ++j) pR[j] += __shfl_xor(pR[j], off, 64);
  }
  if (lane == 0) {
    anomaly[n] = 1.f / (1.f + __expf(-(pA + ab2[0])));
#pragma unroll
    for (int j = 0; j < 5; ++j) resource[n * 5 + j] = pR[j] + cb2[j];
  }
  if (lane == 32) risk[n] = 1.f / (1.f + __expf(-(pA + rb2[0])));
}

// ---------------- pooling + graph MLP (1 block per graph; batch is SORTED) -------
__global__ void k_pool(const float* __restrict__ emb, const int* __restrict__ batch,
                       const float* __restrict__ gw1, const float* __restrict__ gb1,
                       const float* __restrict__ gw2, const float* __restrict__ gb2,
                       float* __restrict__ logits) {
  const int g = blockIdx.x;
  const int tid = threadIdx.x;
  const int c = tid & 63, w = tid >> 6;
  // lower_bound(batch, g) and lower_bound(batch, g+1) on the sorted batch vector
  int lo = 0, hi = NN;
  while (lo < hi) { int mid = (lo + hi) >> 1; if (batch[mid] < g) lo = mid + 1; else hi = mid; }
  const int start = lo;
  hi = NN;
  while (lo < hi) { int mid = (lo + hi) >> 1; if (batch[mid] < g + 1) lo = mid + 1; else hi = mid; }
  const int end = lo;

  float s = 0.f;
  for (int n = start + w; n < end; n += 4) s += emb[n * 64 + c];
  __shared__ float sm[4][64];
  sm[w][c] = s;
  __syncthreads();
  __shared__ float prow[64];
  if (tid < 64) {
    float v = sm[0][tid] + sm[1][tid] + sm[2][tid] + sm[3][tid];
    prow[tid] = v * (1.f / fmaxf((float)(end - start), 1.f));
  }
  __syncthreads();
  if (tid < 32) {
    float hG = gb1[tid];
    for (int cc = 0; cc < 64; ++cc) hG = fmaf(prow[cc], gw1[cc * 32 + tid], hG);
    hG = fmaxf(hG, 0.f);
    float p[4];
#pragma unroll
    for (int j = 0; j < 4; ++j) p[j] = hG * gw2[tid * 4 + j];
#pragma unroll
    for (int off = 1; off <= 16; off <<= 1) {
#pragma unroll
      for (int j = 0; j < 4; ++j) p[j] += __shfl_xor(p[j], off, 64);
    }
    if (tid == 0) {
#pragma unroll
      for (int j = 0; j < 4; ++j) logits[g * 4 + j] = p[j] + gb2[j];
    }
  }
}

extern "C" void kernel_launch(void* const* d_in, const int* in_sizes, int n_in,
                              void* d_out, int out_size, void* d_ws, size_t ws_size,
                              hipStream_t stream) {
  const float* x = (const float*)d_in[0];
  const int* ei = (const int*)d_in[1];
  const int* batch = (const int*)d_in[2];
  const float* W1 = (const float*)d_in[3];
  const float* as1 = (const float*)d_in[4];
  const float* ad1 = (const float*)d_in[5];
  const float* b1 = (const float*)d_in[6];
  const float* W2 = (const float*)d_in[7];
  const float* as2 = (const float*)d_in[8];
  const float* ad2 = (const float*)d_in[9];
  const float* b2 = (const float*)d_in[10];
  const float* W3 = (const float*)d_in[11];
  const float* as3 = (const float*)d_in[12];
  const float* ad3 = (const float*)d_in[13];
  const float* b3 = (const float*)d_in[14];
  const float* aw1 = (const float*)d_in[15];
  const float* ab1 = (const float*)d_in[16];
  const float* aw2 = (const float*)d_in[17];
  const float* ab2 = (const float*)d_in[18];
  const float* rw1 = (const float*)d_in[19];
  const float* rb1 = (const float*)d_in[20];
  const float* rw2 = (const float*)d_in[21];
  const float* rb2 = (const float*)d_in[22];
  const float* cw1 = (const float*)d_in[23];
  const float* cb1 = (const float*)d_in[24];
  const float* cw2 = (const float*)d_in[25];
  const float* cb2 = (const float*)d_in[26];
  const float* gw1 = (const float*)d_in[27];
  const float* gb1 = (const float*)d_in[28];
  const float* gw2 = (const float*)d_in[29];
  const float* gb2 = (const float*)d_in[30];

  float* out = (float*)d_out;
  float* emb = out;                       // [N,64]
  float* anomaly = out + NN * 64;         // [N]
  float* risk = anomaly + NN;             // [N]
  float* resource = risk + NN;            // [N,5]
  float* logits = resource + NN * 5;      // [G,4]

  char* ws = (char*)d_ws;
  int* deg = (int*)ws;            ws += (size_t)NN * 4;
  int* cursor = (int*)ws;         ws += (size_t)NN * 4;
  size_t zbytes = (size_t)(NN * 2) * 4;
  int* offs = (int*)ws;           ws += (size_t)(NN + 4) * 4;  // padded to 16B
  int* csr = (int*)ws;            ws += (size_t)ET * 4;
  float* h = (float*)ws;          ws += (size_t)NN * 256 * 4;
  float* al = (float*)ws;         ws += (size_t)NN * 8 * 4;
  float* xbuf = (float*)ws;       ws += (size_t)NN * 64 * 4;

  hipMemsetAsync(d_ws, 0, zbytes, stream);
  k_count<<<(ET + 255) / 256, 256, 0, stream>>>(ei, deg);
  k_scan<<<1, 1024, 0, stream>>>(deg, offs);
  k_fill<<<(ET + 255) / 256, 256, 0, stream>>>(ei, offs, cursor, csr);

  // layer 1
  k_lin<128><<<NN / 8, 256, 0, stream>>>(x, W1, as1, ad1, h, al);
  k_agg<<<NN / 4, 256, 0, stream>>>(h, al, offs, csr, b1, xbuf, 1);
  // layer 2
  k_lin<64><<<NN / 8, 256, 0, stream>>>(xbuf, W2, as2, ad2, h, al);
  k_agg<<<NN / 4, 256, 0, stream>>>(h, al, offs, csr, b2, xbuf, 1);
  // layer 3
  k_lin<64><<<NN / 8, 256, 0, stream>>>(xbuf, W3, as3, ad3, h, al);
  k_agg<<<NN / 4, 256, 0, stream>>>(h, al, offs, csr, b3, emb, 0);

  k_heads<<<NN / 4, 256, 0, stream>>>(emb, aw1, ab1, aw2, ab2, rw1, rb1, rw2, rb2,
                                      cw1, cb1, cw2, cb2, anomaly, risk, resource);
  k_pool<<<GG, 256, 0, stream>>>(emb, batch, gw1, gb1, gw2, gb2, logits);
}

// Round 3
// 918.208 us; speedup vs baseline: 1.4270x; 1.1402x over previous
//
#include <hip/hip_runtime.h>
#include <hip/hip_fp16.h>
#include <math.h>

#define NN 50000
#define EE 800000
#define ET (NN + EE)   // 850000 edges incl. self-loops
#define GG 64

__device__ __forceinline__ float lrelu(float x) { return x > 0.f ? x : 0.2f * x; }

// ---------------- CSR build ----------------
__global__ void k_count(const int* __restrict__ ei, int* __restrict__ deg) {
  int e = blockIdx.x * 256 + threadIdx.x;
  if (e >= ET) return;
  int dst = (e < EE) ? ei[EE + e] : (e - EE);
  atomicAdd(&deg[dst], 1);
}

__global__ void k_scan(const int* __restrict__ deg, int* __restrict__ offs) {
  __shared__ int s[1024];
  __shared__ int carry_s;
  if (threadIdx.x == 0) carry_s = 0;
  __syncthreads();
  for (int base = 0; base < NN; base += 1024) {
    int i = base + threadIdx.x;
    int v = (i < NN) ? deg[i] : 0;
    s[threadIdx.x] = v;
    __syncthreads();
    for (int off = 1; off < 1024; off <<= 1) {
      int t = (threadIdx.x >= off) ? s[threadIdx.x - off] : 0;
      __syncthreads();
      s[threadIdx.x] += t;
      __syncthreads();
    }
    int c = carry_s;
    if (i < NN) offs[i] = c + s[threadIdx.x] - v;  // exclusive
    int tot = s[1023];
    __syncthreads();
    if (threadIdx.x == 0) carry_s = c + tot;
    __syncthreads();
  }
  if (threadIdx.x == 0) offs[NN] = carry_s;
}

__global__ void k_fill(const int* __restrict__ ei, const int* __restrict__ offs,
                       int* __restrict__ cursor, int* __restrict__ csr) {
  int e = blockIdx.x * 256 + threadIdx.x;
  if (e >= ET) return;
  int src, dst;
  if (e < EE) { src = ei[e]; dst = ei[EE + e]; } else { src = dst = e - EE; }
  int slot = offs[dst] + atomicAdd(&cursor[dst], 1);
  csr[slot] = src;
}

// ---------------- h = x@W (fp16 out)  +  al_s/al_d (fused, fp32) ----------------
// block: 256 threads -> 8 rows x 256 cols. Wave w == head w for the al reduce.
template <int K>
__global__ void k_lin(const float* __restrict__ xin, const float* __restrict__ W,
                      const float* __restrict__ a_s, const float* __restrict__ a_d,
                      __half* __restrict__ h, float* __restrict__ al) {
  __shared__ float xs[8 * K];
  const int c = threadIdx.x;
  const int row0 = blockIdx.x * 8;
  for (int i = c; i < 8 * K; i += 256) xs[i] = xin[row0 * K + i];
  __syncthreads();
  float acc[8] = {};
  for (int k = 0; k < K; ++k) {
    float w = W[k * 256 + c];
#pragma unroll
    for (int r = 0; r < 8; ++r) acc[r] = fmaf(xs[r * K + k], w, acc[r]);
  }
  const float asc = a_s[c], adc = a_d[c];
#pragma unroll
  for (int r = 0; r < 8; ++r) h[(row0 + r) * 256 + c] = __float2half(acc[r]);
  float ps[8], pd[8];
#pragma unroll
  for (int r = 0; r < 8; ++r) { ps[r] = acc[r] * asc; pd[r] = acc[r] * adc; }
#pragma unroll
  for (int off = 32; off >= 1; off >>= 1) {
#pragma unroll
    for (int r = 0; r < 8; ++r) {
      ps[r] += __shfl_xor(ps[r], off, 64);
      pd[r] += __shfl_xor(pd[r], off, 64);
    }
  }
  if ((c & 63) == 0) {
    int head = c >> 6;
#pragma unroll
    for (int r = 0; r < 8; ++r) {
      al[(row0 + r) * 8 + head] = ps[r];
      al[(row0 + r) * 8 + 4 + head] = pd[r];
    }
  }
}

// ---------------- per-dst softmax + aggregate (wave per node, single pass) --------
// No max-subtraction: edge logits are O(+-10), exp() is safe in fp32, and the
// max cancels exactly in p/denom. h gathered in fp16 (512 B/row).
__global__ void k_agg(const __half* __restrict__ h, const float* __restrict__ al,
                      const int* __restrict__ offs, const int* __restrict__ csr,
                      const float* __restrict__ bias, float* __restrict__ out,
                      const int do_relu) {
  const int lane = threadIdx.x & 63;
  const int n = blockIdx.x * 4 + (threadIdx.x >> 6);
  const int head = lane >> 4;
  const int start = offs[n], end = offs[n + 1];
  const float ald_my = al[n * 8 + 4 + head];
  float ax = 0.f, ay = 0.f, az = 0.f, aw = 0.f, denom = 0.f;
  for (int i = start; i < end; ++i) {
    int s = csr[i];
    float p = __expf(lrelu(al[s * 8 + head] + ald_my));
    denom += p;
    union { ushort4 u; __half2 h2[2]; } cv;
    cv.u = *(const ushort4*)(h + s * 256 + lane * 4);
    float2 f01 = __half22float2(cv.h2[0]);
    float2 f23 = __half22float2(cv.h2[1]);
    ax = fmaf(p, f01.x, ax);
    ay = fmaf(p, f01.y, ay);
    az = fmaf(p, f23.x, az);
    aw = fmaf(p, f23.y, aw);
  }
  const float inv = 0.25f / denom;  // alpha normalize + head mean
  ax *= inv; ay *= inv; az *= inv; aw *= inv;
  ax += __shfl_xor(ax, 16, 64); ax += __shfl_xor(ax, 32, 64);
  ay += __shfl_xor(ay, 16, 64); ay += __shfl_xor(ay, 32, 64);
  az += __shfl_xor(az, 16, 64); az += __shfl_xor(az, 32, 64);
  aw += __shfl_xor(aw, 16, 64); aw += __shfl_xor(aw, 32, 64);
  if (lane < 16) {
    const float4 b4 = *(const float4*)&bias[lane * 4];
    float4 o;
    o.x = ax + b4.x; o.y = ay + b4.y; o.z = az + b4.z; o.w = aw + b4.w;
    if (do_relu) {
      o.x = fmaxf(o.x, 0.f); o.y = fmaxf(o.y, 0.f);
      o.z = fmaxf(o.z, 0.f); o.w = fmaxf(o.w, 0.f);
    }
    *(float4*)&out[n * 64 + lane * 4] = o;
  }
}

// ---------------- node MLP heads (wave per node; no atomics) ----------------
__global__ void k_heads(const float* __restrict__ emb,
                        const float* __restrict__ aw1, const float* __restrict__ ab1,
                        const float* __restrict__ aw2, const float* __restrict__ ab2,
                        const float* __restrict__ rw1, const float* __restrict__ rb1,
                        const float* __restrict__ rw2, const float* __restrict__ rb2,
                        const float* __restrict__ cw1, const float* __restrict__ cb1,
                        const float* __restrict__ cw2, const float* __restrict__ cb2,
                        float* __restrict__ anomaly, float* __restrict__ risk,
                        float* __restrict__ resource) {
  const int lane = threadIdx.x & 63;
  const int n = blockIdx.x * 4 + (threadIdx.x >> 6);
  const float e = emb[n * 64 + lane];
  const int k = lane & 31;
  const bool hi = lane >= 32;
  const float* w1 = hi ? rw1 : aw1;
  const float* b1 = hi ? rb1 : ab1;
  float hA = b1[k];
  float hC = cb1[k];
  for (int cc = 0; cc < 64; ++cc) {
    float bc = __shfl(e, cc, 64);
    hA = fmaf(bc, w1[cc * 32 + k], hA);
    hC = fmaf(bc, cw1[cc * 32 + k], hC);
  }
  hA = fmaxf(hA, 0.f);
  hC = fmaxf(hC, 0.f);
  const float* w2 = hi ? rw2 : aw2;
  float pA = hA * w2[k];
  float pR[5];
#pragma unroll
  for (int j = 0; j < 5; ++j) pR[j] = hC * cw2[k * 5 + j];
#pragma unroll
  for (int off = 1; off <= 16; off <<= 1) {
    pA += __shfl_xor(pA, off, 64);
#pragma unroll
    for (int j = 0; j < 5; ++j) pR[j] += __shfl_xor(pR[j], off, 64);
  }
  if (lane == 0) {
    anomaly[n] = 1.f / (1.f + __expf(-(pA + ab2[0])));
#pragma unroll
    for (int j = 0; j < 5; ++j) resource[n * 5 + j] = pR[j] + cb2[j];
  }
  if (lane == 32) risk[n] = 1.f / (1.f + __expf(-(pA + rb2[0])));
}

// ---------------- pooling + graph MLP (1 block per graph; batch is SORTED) -------
__global__ void k_pool(const float* __restrict__ emb, const int* __restrict__ batch,
                       const float* __restrict__ gw1, const float* __restrict__ gb1,
                       const float* __restrict__ gw2, const float* __restrict__ gb2,
                       float* __restrict__ logits) {
  const int g = blockIdx.x;
  const int tid = threadIdx.x;
  const int c = tid & 63, w = tid >> 6;
  int lo = 0, hi = NN;
  while (lo < hi) { int mid = (lo + hi) >> 1; if (batch[mid] < g) lo = mid + 1; else hi = mid; }
  const int start = lo;
  hi = NN;
  while (lo < hi) { int mid = (lo + hi) >> 1; if (batch[mid] < g + 1) lo = mid + 1; else hi = mid; }
  const int end = lo;

  float s = 0.f;
  for (int n = start + w; n < end; n += 4) s += emb[n * 64 + c];
  __shared__ float sm[4][64];
  sm[w][c] = s;
  __syncthreads();
  __shared__ float prow[64];
  if (tid < 64) {
    float v = sm[0][tid] + sm[1][tid] + sm[2][tid] + sm[3][tid];
    prow[tid] = v * (1.f / fmaxf((float)(end - start), 1.f));
  }
  __syncthreads();
  if (tid < 32) {
    float hG = gb1[tid];
    for (int cc = 0; cc < 64; ++cc) hG = fmaf(prow[cc], gw1[cc * 32 + tid], hG);
    hG = fmaxf(hG, 0.f);
    float p[4];
#pragma unroll
    for (int j = 0; j < 4; ++j) p[j] = hG * gw2[tid * 4 + j];
#pragma unroll
    for (int off = 1; off <= 16; off <<= 1) {
#pragma unroll
      for (int j = 0; j < 4; ++j) p[j] += __shfl_xor(p[j], off, 64);
    }
    if (tid == 0) {
#pragma unroll
      for (int j = 0; j < 4; ++j) logits[g * 4 + j] = p[j] + gb2[j];
    }
  }
}

extern "C" void kernel_launch(void* const* d_in, const int* in_sizes, int n_in,
                              void* d_out, int out_size, void* d_ws, size_t ws_size,
                              hipStream_t stream) {
  const float* x = (const float*)d_in[0];
  const int* ei = (const int*)d_in[1];
  const int* batch = (const int*)d_in[2];
  const float* W1 = (const float*)d_in[3];
  const float* as1 = (const float*)d_in[4];
  const float* ad1 = (const float*)d_in[5];
  const float* b1 = (const float*)d_in[6];
  const float* W2 = (const float*)d_in[7];
  const float* as2 = (const float*)d_in[8];
  const float* ad2 = (const float*)d_in[9];
  const float* b2 = (const float*)d_in[10];
  const float* W3 = (const float*)d_in[11];
  const float* as3 = (const float*)d_in[12];
  const float* ad3 = (const float*)d_in[13];
  const float* b3 = (const float*)d_in[14];
  const float* aw1 = (const float*)d_in[15];
  const float* ab1 = (const float*)d_in[16];
  const float* aw2 = (const float*)d_in[17];
  const float* ab2 = (const float*)d_in[18];
  const float* rw1 = (const float*)d_in[19];
  const float* rb1 = (const float*)d_in[20];
  const float* rw2 = (const float*)d_in[21];
  const float* rb2 = (const float*)d_in[22];
  const float* cw1 = (const float*)d_in[23];
  const float* cb1 = (const float*)d_in[24];
  const float* cw2 = (const float*)d_in[25];
  const float* cb2 = (const float*)d_in[26];
  const float* gw1 = (const float*)d_in[27];
  const float* gb1 = (const float*)d_in[28];
  const float* gw2 = (const float*)d_in[29];
  const float* gb2 = (const float*)d_in[30];

  float* out = (float*)d_out;
  float* emb = out;                       // [N,64]
  float* anomaly = out + NN * 64;         // [N]
  float* risk = anomaly + NN;             // [N]
  float* resource = risk + NN;            // [N,5]
  float* logits = resource + NN * 5;      // [G,4]

  char* ws = (char*)d_ws;
  int* deg = (int*)ws;            ws += (size_t)NN * 4;
  int* cursor = (int*)ws;         ws += (size_t)NN * 4;
  size_t zbytes = (size_t)(NN * 2) * 4;
  int* offs = (int*)ws;           ws += (size_t)(NN + 4) * 4;  // padded to 16B
  int* csr = (int*)ws;            ws += (size_t)ET * 4;
  __half* h = (__half*)ws;        ws += (size_t)NN * 256 * 2;
  float* al = (float*)ws;         ws += (size_t)NN * 8 * 4;
  float* xbuf = (float*)ws;       ws += (size_t)NN * 64 * 4;

  hipMemsetAsync(d_ws, 0, zbytes, stream);
  k_count<<<(ET + 255) / 256, 256, 0, stream>>>(ei, deg);
  k_scan<<<1, 1024, 0, stream>>>(deg, offs);
  k_fill<<<(ET + 255) / 256, 256, 0, stream>>>(ei, offs, cursor, csr);

  // layer 1
  k_lin<128><<<NN / 8, 256, 0, stream>>>(x, W1, as1, ad1, h, al);
  k_agg<<<NN / 4, 256, 0, stream>>>(h, al, offs, csr, b1, xbuf, 1);
  // layer 2
  k_lin<64><<<NN / 8, 256, 0, stream>>>(xbuf, W2, as2, ad2, h, al);
  k_agg<<<NN / 4, 256, 0, stream>>>(h, al, offs, csr, b2, xbuf, 1);
  // layer 3
  k_lin<64><<<NN / 8, 256, 0, stream>>>(xbuf, W3, as3, ad3, h, al);
  k_agg<<<NN / 4, 256, 0, stream>>>(h, al, offs, csr, b3, emb, 0);

  k_heads<<<NN / 4, 256, 0, stream>>>(emb, aw1, ab1, aw2, ab2, rw1, rb1, rw2, rb2,
                                      cw1, cb1, cw2, cb2, anomaly, risk, resource);
  k_pool<<<GG, 256, 0, stream>>>(emb, batch, gw1, gb1, gw2, gb2, logits);
}

// Round 4
// 749.529 us; speedup vs baseline: 1.7482x; 1.2250x over previous
//
#include <hip/hip_runtime.h>
#include <hip/hip_fp16.h>
#include <math.h>

#define NN 50000
#define EE 800000
#define ET (NN + EE)   // 850000 edges incl. self-loops
#define GG 64
#define NCH ((NN + 255) / 256)   // 196 chunks for the hierarchical scan

__device__ __forceinline__ float lrelu(float x) { return x > 0.f ? x : 0.2f * x; }

// ---------------- CSR build ----------------
__global__ void k_count(const int* __restrict__ ei, int* __restrict__ deg) {
  int e = blockIdx.x * 256 + threadIdx.x;
  if (e >= ET) return;
  int dst = (e < EE) ? ei[EE + e] : (e - EE);
  atomicAdd(&deg[dst], 1);
}

// hierarchical exclusive scan of deg[NN] -> offs[NN+1]
__global__ void k_scan1(const int* __restrict__ deg, int* __restrict__ csum) {
  const int i = blockIdx.x * 256 + threadIdx.x;
  int v = (i < NN) ? deg[i] : 0;
#pragma unroll
  for (int off = 32; off >= 1; off >>= 1) v += __shfl_xor(v, off, 64);
  __shared__ int sm[4];
  if ((threadIdx.x & 63) == 0) sm[threadIdx.x >> 6] = v;
  __syncthreads();
  if (threadIdx.x == 0) csum[blockIdx.x] = sm[0] + sm[1] + sm[2] + sm[3];
}

__global__ void k_scan2(const int* __restrict__ csum, int* __restrict__ cbase,
                        int* __restrict__ offs) {
  __shared__ int s[256];
  const int t = threadIdx.x;
  int v = (t < NCH) ? csum[t] : 0;
  s[t] = v;
  __syncthreads();
  for (int off = 1; off < 256; off <<= 1) {
    int u = (t >= off) ? s[t - off] : 0;
    __syncthreads();
    s[t] += u;
    __syncthreads();
  }
  cbase[t] = s[t] - v;          // exclusive chunk base
  if (t == 255) offs[NN] = s[255];
}

__global__ void k_scan3(const int* __restrict__ deg, const int* __restrict__ cbase,
                        int* __restrict__ offs) {
  __shared__ int s[256];
  const int t = threadIdx.x;
  const int i = blockIdx.x * 256 + t;
  int v = (i < NN) ? deg[i] : 0;
  s[t] = v;
  __syncthreads();
  for (int off = 1; off < 256; off <<= 1) {
    int u = (t >= off) ? s[t - off] : 0;
    __syncthreads();
    s[t] += u;
    __syncthreads();
  }
  if (i < NN) offs[i] = cbase[blockIdx.x] + s[t] - v;  // exclusive
}

__global__ void k_fill(const int* __restrict__ ei, const int* __restrict__ offs,
                       int* __restrict__ cursor, int* __restrict__ csr) {
  int e = blockIdx.x * 256 + threadIdx.x;
  if (e >= ET) return;
  int src, dst;
  if (e < EE) { src = ei[e]; dst = ei[EE + e]; } else { src = dst = e - EE; }
  int slot = offs[dst] + atomicAdd(&cursor[dst], 1);
  csr[slot] = src;
}

// ---------------- h = x@W (fp16 out)  +  al_s/al_d (fused, fp32) ----------------
template <int K>
__global__ void k_lin(const float* __restrict__ xin, const float* __restrict__ W,
                      const float* __restrict__ a_s, const float* __restrict__ a_d,
                      __half* __restrict__ h, float* __restrict__ al) {
  __shared__ float xs[8 * K];
  const int c = threadIdx.x;
  const int row0 = blockIdx.x * 8;
  for (int i = c; i < 8 * K; i += 256) xs[i] = xin[row0 * K + i];
  __syncthreads();
  float acc[8] = {};
  for (int k = 0; k < K; ++k) {
    float w = W[k * 256 + c];
#pragma unroll
    for (int r = 0; r < 8; ++r) acc[r] = fmaf(xs[r * K + k], w, acc[r]);
  }
  const float asc = a_s[c], adc = a_d[c];
#pragma unroll
  for (int r = 0; r < 8; ++r) h[(row0 + r) * 256 + c] = __float2half(acc[r]);
  float ps[8], pd[8];
#pragma unroll
  for (int r = 0; r < 8; ++r) { ps[r] = acc[r] * asc; pd[r] = acc[r] * adc; }
#pragma unroll
  for (int off = 32; off >= 1; off >>= 1) {
#pragma unroll
    for (int r = 0; r < 8; ++r) {
      ps[r] += __shfl_xor(ps[r], off, 64);
      pd[r] += __shfl_xor(pd[r], off, 64);
    }
  }
  if ((c & 63) == 0) {
    int head = c >> 6;
#pragma unroll
    for (int r = 0; r < 8; ++r) {
      al[(row0 + r) * 8 + head] = ps[r];
      al[(row0 + r) * 8 + 4 + head] = pd[r];
    }
  }
}

// ---------------- per-dst softmax + aggregate (wave per node, unrolled x4) --------
__global__ void k_agg(const __half* __restrict__ h, const float* __restrict__ al,
                      const int* __restrict__ offs, const int* __restrict__ csr,
                      const float* __restrict__ bias, float* __restrict__ out,
                      const int do_relu) {
  const int lane = threadIdx.x & 63;
  const int n = blockIdx.x * 4 + (threadIdx.x >> 6);
  const int head = lane >> 4;
  const int start = offs[n], end = offs[n + 1];
  const float ald_my = al[n * 8 + 4 + head];
  float ax = 0.f, ay = 0.f, az = 0.f, aw = 0.f, denom = 0.f;
  int i = start;
  const int e4 = start + ((end - start) & ~3);
  for (; i < e4; i += 4) {
    const int s0 = csr[i], s1 = csr[i + 1], s2 = csr[i + 2], s3 = csr[i + 3];
    union { ushort4 u; __half2 h2[2]; } c0, c1, c2, c3;
    c0.u = *(const ushort4*)(h + s0 * 256 + lane * 4);
    c1.u = *(const ushort4*)(h + s1 * 256 + lane * 4);
    c2.u = *(const ushort4*)(h + s2 * 256 + lane * 4);
    c3.u = *(const ushort4*)(h + s3 * 256 + lane * 4);
    const float p0 = __expf(lrelu(al[s0 * 8 + head] + ald_my));
    const float p1 = __expf(lrelu(al[s1 * 8 + head] + ald_my));
    const float p2 = __expf(lrelu(al[s2 * 8 + head] + ald_my));
    const float p3 = __expf(lrelu(al[s3 * 8 + head] + ald_my));
    denom += (p0 + p1) + (p2 + p3);
    float2 f;
    f = __half22float2(c0.h2[0]); ax = fmaf(p0, f.x, ax); ay = fmaf(p0, f.y, ay);
    f = __half22float2(c0.h2[1]); az = fmaf(p0, f.x, az); aw = fmaf(p0, f.y, aw);
    f = __half22float2(c1.h2[0]); ax = fmaf(p1, f.x, ax); ay = fmaf(p1, f.y, ay);
    f = __half22float2(c1.h2[1]); az = fmaf(p1, f.x, az); aw = fmaf(p1, f.y, aw);
    f = __half22float2(c2.h2[0]); ax = fmaf(p2, f.x, ax); ay = fmaf(p2, f.y, ay);
    f = __half22float2(c2.h2[1]); az = fmaf(p2, f.x, az); aw = fmaf(p2, f.y, aw);
    f = __half22float2(c3.h2[0]); ax = fmaf(p3, f.x, ax); ay = fmaf(p3, f.y, ay);
    f = __half22float2(c3.h2[1]); az = fmaf(p3, f.x, az); aw = fmaf(p3, f.y, aw);
  }
  for (; i < end; ++i) {
    const int s = csr[i];
    union { ushort4 u; __half2 h2[2]; } cv;
    cv.u = *(const ushort4*)(h + s * 256 + lane * 4);
    const float p = __expf(lrelu(al[s * 8 + head] + ald_my));
    denom += p;
    float2 f;
    f = __half22float2(cv.h2[0]); ax = fmaf(p, f.x, ax); ay = fmaf(p, f.y, ay);
    f = __half22float2(cv.h2[1]); az = fmaf(p, f.x, az); aw = fmaf(p, f.y, aw);
  }
  const float inv = 0.25f / denom;  // alpha normalize + head mean
  ax *= inv; ay *= inv; az *= inv; aw *= inv;
  ax += __shfl_xor(ax, 16, 64); ax += __shfl_xor(ax, 32, 64);
  ay += __shfl_xor(ay, 16, 64); ay += __shfl_xor(ay, 32, 64);
  az += __shfl_xor(az, 16, 64); az += __shfl_xor(az, 32, 64);
  aw += __shfl_xor(aw, 16, 64); aw += __shfl_xor(aw, 32, 64);
  if (lane < 16) {
    const float4 b4 = *(const float4*)&bias[lane * 4];
    float4 o;
    o.x = ax + b4.x; o.y = ay + b4.y; o.z = az + b4.z; o.w = aw + b4.w;
    if (do_relu) {
      o.x = fmaxf(o.x, 0.f); o.y = fmaxf(o.y, 0.f);
      o.z = fmaxf(o.z, 0.f); o.w = fmaxf(o.w, 0.f);
    }
    *(float4*)&out[n * 64 + lane * 4] = o;
  }
}

// ---------------- node MLP heads (wave per node; no atomics) ----------------
__global__ void k_heads(const float* __restrict__ emb,
                        const float* __restrict__ aw1, const float* __restrict__ ab1,
                        const float* __restrict__ aw2, const float* __restrict__ ab2,
                        const float* __restrict__ rw1, const float* __restrict__ rb1,
                        const float* __restrict__ rw2, const float* __restrict__ rb2,
                        const float* __restrict__ cw1, const float* __restrict__ cb1,
                        const float* __restrict__ cw2, const float* __restrict__ cb2,
                        float* __restrict__ anomaly, float* __restrict__ risk,
                        float* __restrict__ resource) {
  const int lane = threadIdx.x & 63;
  const int n = blockIdx.x * 4 + (threadIdx.x >> 6);
  const float e = emb[n * 64 + lane];
  const int k = lane & 31;
  const bool hi = lane >= 32;
  const float* w1 = hi ? rw1 : aw1;
  const float* b1 = hi ? rb1 : ab1;
  float hA = b1[k];
  float hC = cb1[k];
  for (int cc = 0; cc < 64; ++cc) {
    float bc = __shfl(e, cc, 64);
    hA = fmaf(bc, w1[cc * 32 + k], hA);
    hC = fmaf(bc, cw1[cc * 32 + k], hC);
  }
  hA = fmaxf(hA, 0.f);
  hC = fmaxf(hC, 0.f);
  const float* w2 = hi ? rw2 : aw2;
  float pA = hA * w2[k];
  float pR[5];
#pragma unroll
  for (int j = 0; j < 5; ++j) pR[j] = hC * cw2[k * 5 + j];
#pragma unroll
  for (int off = 1; off <= 16; off <<= 1) {
    pA += __shfl_xor(pA, off, 64);
#pragma unroll
    for (int j = 0; j < 5; ++j) pR[j] += __shfl_xor(pR[j], off, 64);
  }
  if (lane == 0) {
    anomaly[n] = 1.f / (1.f + __expf(-(pA + ab2[0])));
#pragma unroll
    for (int j = 0; j < 5; ++j) resource[n * 5 + j] = pR[j] + cb2[j];
  }
  if (lane == 32) risk[n] = 1.f / (1.f + __expf(-(pA + rb2[0])));
}

// ---------------- pooling + graph MLP (1 block per graph; batch is SORTED) -------
__global__ void k_pool(const float* __restrict__ emb, const int* __restrict__ batch,
                       const float* __restrict__ gw1, const float* __restrict__ gb1,
                       const float* __restrict__ gw2, const float* __restrict__ gb2,
                       float* __restrict__ logits) {
  const int g = blockIdx.x;
  const int tid = threadIdx.x;
  const int c = tid & 63, w = tid >> 6;
  int lo = 0, hi = NN;
  while (lo < hi) { int mid = (lo + hi) >> 1; if (batch[mid] < g) lo = mid + 1; else hi = mid; }
  const int start = lo;
  hi = NN;
  while (lo < hi) { int mid = (lo + hi) >> 1; if (batch[mid] < g + 1) lo = mid + 1; else hi = mid; }
  const int end = lo;

  float s = 0.f;
  for (int n = start + w; n < end; n += 4) s += emb[n * 64 + c];
  __shared__ float sm[4][64];
  sm[w][c] = s;
  __syncthreads();
  __shared__ float prow[64];
  if (tid < 64) {
    float v = sm[0][tid] + sm[1][tid] + sm[2][tid] + sm[3][tid];
    prow[tid] = v * (1.f / fmaxf((float)(end - start), 1.f));
  }
  __syncthreads();
  if (tid < 32) {
    float hG = gb1[tid];
    for (int cc = 0; cc < 64; ++cc) hG = fmaf(prow[cc], gw1[cc * 32 + tid], hG);
    hG = fmaxf(hG, 0.f);
    float p[4];
#pragma unroll
    for (int j = 0; j < 4; ++j) p[j] = hG * gw2[tid * 4 + j];
#pragma unroll
    for (int off = 1; off <= 16; off <<= 1) {
#pragma unroll
      for (int j = 0; j < 4; ++j) p[j] += __shfl_xor(p[j], off, 64);
    }
    if (tid == 0) {
#pragma unroll
      for (int j = 0; j < 4; ++j) logits[g * 4 + j] = p[j] + gb2[j];
    }
  }
}

extern "C" void kernel_launch(void* const* d_in, const int* in_sizes, int n_in,
                              void* d_out, int out_size, void* d_ws, size_t ws_size,
                              hipStream_t stream) {
  const float* x = (const float*)d_in[0];
  const int* ei = (const int*)d_in[1];
  const int* batch = (const int*)d_in[2];
  const float* W1 = (const float*)d_in[3];
  const float* as1 = (const float*)d_in[4];
  const float* ad1 = (const float*)d_in[5];
  const float* b1 = (const float*)d_in[6];
  const float* W2 = (const float*)d_in[7];
  const float* as2 = (const float*)d_in[8];
  const float* ad2 = (const float*)d_in[9];
  const float* b2 = (const float*)d_in[10];
  const float* W3 = (const float*)d_in[11];
  const float* as3 = (const float*)d_in[12];
  const float* ad3 = (const float*)d_in[13];
  const float* b3 = (const float*)d_in[14];
  const float* aw1 = (const float*)d_in[15];
  const float* ab1 = (const float*)d_in[16];
  const float* aw2 = (const float*)d_in[17];
  const float* ab2 = (const float*)d_in[18];
  const float* rw1 = (const float*)d_in[19];
  const float* rb1 = (const float*)d_in[20];
  const float* rw2 = (const float*)d_in[21];
  const float* rb2 = (const float*)d_in[22];
  const float* cw1 = (const float*)d_in[23];
  const float* cb1 = (const float*)d_in[24];
  const float* cw2 = (const float*)d_in[25];
  const float* cb2 = (const float*)d_in[26];
  const float* gw1 = (const float*)d_in[27];
  const float* gb1 = (const float*)d_in[28];
  const float* gw2 = (const float*)d_in[29];
  const float* gb2 = (const float*)d_in[30];

  float* out = (float*)d_out;
  float* emb = out;                       // [N,64]
  float* anomaly = out + NN * 64;         // [N]
  float* risk = anomaly + NN;             // [N]
  float* resource = risk + NN;            // [N,5]
  float* logits = resource + NN * 5;      // [G,4]

  char* ws = (char*)d_ws;
  int* deg = (int*)ws;            ws += (size_t)NN * 4;
  int* cursor = (int*)ws;         ws += (size_t)NN * 4;
  size_t zbytes = (size_t)(NN * 2) * 4;
  int* offs = (int*)ws;           ws += (size_t)(NN + 4) * 4;  // padded to 16B
  int* csum = (int*)ws;           ws += 256 * 4;
  int* cbase = (int*)ws;          ws += 256 * 4;
  int* csr = (int*)ws;            ws += (size_t)ET * 4;
  __half* h = (__half*)ws;        ws += (size_t)NN * 256 * 2;
  float* al = (float*)ws;         ws += (size_t)NN * 8 * 4;
  float* xbuf = (float*)ws;       ws += (size_t)NN * 64 * 4;

  hipMemsetAsync(d_ws, 0, zbytes, stream);
  k_count<<<(ET + 255) / 256, 256, 0, stream>>>(ei, deg);
  k_scan1<<<NCH, 256, 0, stream>>>(deg, csum);
  k_scan2<<<1, 256, 0, stream>>>(csum, cbase, offs);
  k_scan3<<<NCH, 256, 0, stream>>>(deg, cbase, offs);
  k_fill<<<(ET + 255) / 256, 256, 0, stream>>>(ei, offs, cursor, csr);

  // layer 1
  k_lin<128><<<NN / 8, 256, 0, stream>>>(x, W1, as1, ad1, h, al);
  k_agg<<<NN / 4, 256, 0, stream>>>(h, al, offs, csr, b1, xbuf, 1);
  // layer 2
  k_lin<64><<<NN / 8, 256, 0, stream>>>(xbuf, W2, as2, ad2, h, al);
  k_agg<<<NN / 4, 256, 0, stream>>>(h, al, offs, csr, b2, xbuf, 1);
  // layer 3
  k_lin<64><<<NN / 8, 256, 0, stream>>>(xbuf, W3, as3, ad3, h, al);
  k_agg<<<NN / 4, 256, 0, stream>>>(h, al, offs, csr, b3, emb, 0);

  k_heads<<<NN / 4, 256, 0, stream>>>(emb, aw1, ab1, aw2, ab2, rw1, rb1, rw2, rb2,
                                      cw1, cb1, cw2, cb2, anomaly, risk, resource);
  k_pool<<<GG, 256, 0, stream>>>(emb, batch, gw1, gb1, gw2, gb2, logits);
}

// Round 5
// 638.148 us; speedup vs baseline: 2.0533x; 1.1745x over previous
//
#include <hip/hip_runtime.h>
#include <hip/hip_fp16.h>
#include <math.h>

#define NN 50000
#define EE 800000
#define ET (NN + EE)   // 850000 edges incl. self-loops
#define GG 64
#define NCH ((NN + 255) / 256)   // 196 chunks for the hierarchical scan

typedef _Float16 f16x8 __attribute__((ext_vector_type(8)));
typedef float f32x4 __attribute__((ext_vector_type(4)));

__device__ __forceinline__ float lrelu(float x) { return x > 0.f ? x : 0.2f * x; }

// ---------------- CSR build ----------------
__global__ void k_count(const int* __restrict__ ei, int* __restrict__ deg) {
  int e = blockIdx.x * 256 + threadIdx.x;
  if (e >= ET) return;
  int dst = (e < EE) ? ei[EE + e] : (e - EE);
  atomicAdd(&deg[dst], 1);
}

__global__ void k_scan1(const int* __restrict__ deg, int* __restrict__ csum) {
  const int i = blockIdx.x * 256 + threadIdx.x;
  int v = (i < NN) ? deg[i] : 0;
#pragma unroll
  for (int off = 32; off >= 1; off >>= 1) v += __shfl_xor(v, off, 64);
  __shared__ int sm[4];
  if ((threadIdx.x & 63) == 0) sm[threadIdx.x >> 6] = v;
  __syncthreads();
  if (threadIdx.x == 0) csum[blockIdx.x] = sm[0] + sm[1] + sm[2] + sm[3];
}

__global__ void k_scan2(const int* __restrict__ csum, int* __restrict__ cbase,
                        int* __restrict__ offs) {
  __shared__ int s[256];
  const int t = threadIdx.x;
  int v = (t < NCH) ? csum[t] : 0;
  s[t] = v;
  __syncthreads();
  for (int off = 1; off < 256; off <<= 1) {
    int u = (t >= off) ? s[t - off] : 0;
    __syncthreads();
    s[t] += u;
    __syncthreads();
  }
  cbase[t] = s[t] - v;
  if (t == 255) offs[NN] = s[255];
}

__global__ void k_scan3(const int* __restrict__ deg, const int* __restrict__ cbase,
                        int* __restrict__ offs) {
  __shared__ int s[256];
  const int t = threadIdx.x;
  const int i = blockIdx.x * 256 + t;
  int v = (i < NN) ? deg[i] : 0;
  s[t] = v;
  __syncthreads();
  for (int off = 1; off < 256; off <<= 1) {
    int u = (t >= off) ? s[t - off] : 0;
    __syncthreads();
    s[t] += u;
    __syncthreads();
  }
  if (i < NN) offs[i] = cbase[blockIdx.x] + s[t] - v;
}

__global__ void k_fill(const int* __restrict__ ei, const int* __restrict__ offs,
                       int* __restrict__ cursor, int* __restrict__ csr) {
  int e = blockIdx.x * 256 + threadIdx.x;
  if (e >= ET) return;
  int src, dst;
  if (e < EE) { src = ei[e]; dst = ei[EE + e]; } else { src = dst = e - EE; }
  int slot = offs[dst] + atomicAdd(&cursor[dst], 1);
  csr[slot] = src;
}

// ---------------- x fp32 -> fp16 ----------------
__global__ void k_cvt(const float* __restrict__ x, __half2* __restrict__ xh, int n4) {
  int i = blockIdx.x * 256 + threadIdx.x;
  if (i >= n4) return;
  float4 v = ((const float4*)x)[i];
  xh[i * 2] = __floats2half2_rn(v.x, v.y);
  xh[i * 2 + 1] = __floats2half2_rn(v.z, v.w);
}

// ---------------- h = x@W via MFMA 16x16x32 f16 ----------------
// Block = 4 waves; wave w owns cols [64w,64w+64) (4 col-tiles of 16).
// B-frags (W) loaded once per block, reused over grid-stride row-tile loop.
// A frag: lane holds A[m=lane&15][k=quad*8+j] -> contiguous 16B of the x row.
// C/D: lane reg r -> D[row=quad*4+r][col=lane&15].
template <int K>
__global__ __launch_bounds__(256) void k_mm(const __half* __restrict__ xh,
                                            const float* __restrict__ W,
                                            __half* __restrict__ h) {
  constexpr int KC = K / 32;
  const int lane = threadIdx.x & 63;
  const int wv = threadIdx.x >> 6;
  const int quad = lane >> 4, nn = lane & 15;
  f16x8 bf[KC][4];
#pragma unroll
  for (int ct = 0; ct < 4; ++ct) {
    const int col = wv * 64 + ct * 16 + nn;
#pragma unroll
    for (int kc = 0; kc < KC; ++kc)
#pragma unroll
      for (int j = 0; j < 8; ++j)
        bf[kc][ct][j] = (_Float16)W[(kc * 32 + quad * 8 + j) * 256 + col];
  }
  for (int rt = blockIdx.x; rt < NN / 16; rt += gridDim.x) {
    const int row0 = rt * 16;
    const _Float16* xrow = (const _Float16*)xh + (size_t)(row0 + nn) * K + quad * 8;
    f16x8 af[KC];
#pragma unroll
    for (int kc = 0; kc < KC; ++kc) af[kc] = *(const f16x8*)(xrow + kc * 32);
#pragma unroll
    for (int ct = 0; ct < 4; ++ct) {
      f32x4 acc = {0.f, 0.f, 0.f, 0.f};
#pragma unroll
      for (int kc = 0; kc < KC; ++kc)
        acc = __builtin_amdgcn_mfma_f32_16x16x32_f16(af[kc], bf[kc][ct], acc, 0, 0, 0);
      const int col = wv * 64 + ct * 16 + nn;
#pragma unroll
      for (int r = 0; r < 4; ++r)
        h[(size_t)(row0 + quad * 4 + r) * 256 + col] = __float2half(acc[r]);
    }
  }
}

// ---------------- al_s/al_d from h (wave per node) ----------------
__global__ void k_al(const __half* __restrict__ h, const float* __restrict__ a_s,
                     const float* __restrict__ a_d, float* __restrict__ al) {
  const int lane = threadIdx.x & 63;
  const int n = blockIdx.x * 4 + (threadIdx.x >> 6);
  const int head = lane >> 4;
  union { ushort4 u; __half2 h2[2]; } cv;
  cv.u = *(const ushort4*)(h + (size_t)n * 256 + lane * 4);
  float2 f01 = __half22float2(cv.h2[0]);
  float2 f23 = __half22float2(cv.h2[1]);
  const float4 s4 = *(const float4*)&a_s[head * 64 + (lane & 15) * 4];
  const float4 d4 = *(const float4*)&a_d[head * 64 + (lane & 15) * 4];
  float s = f01.x * s4.x + f01.y * s4.y + f23.x * s4.z + f23.y * s4.w;
  float d = f01.x * d4.x + f01.y * d4.y + f23.x * d4.z + f23.y * d4.w;
#pragma unroll
  for (int off = 1; off <= 8; off <<= 1) {
    s += __shfl_xor(s, off, 64);
    d += __shfl_xor(d, off, 64);
  }
  if ((lane & 15) == 0) { al[n * 8 + head] = s; al[n * 8 + 4 + head] = d; }
}

// ---------------- per-dst softmax + aggregate (wave per node, unrolled x4) --------
// mode 1: relu + fp16 store to outh (next layer input). mode 0: fp32 store to outf.
__global__ void k_agg(const __half* __restrict__ h, const float* __restrict__ al,
                      const int* __restrict__ offs, const int* __restrict__ csr,
                      const float* __restrict__ bias, float* __restrict__ outf,
                      __half* __restrict__ outh, const int mode) {
  const int lane = threadIdx.x & 63;
  const int n = blockIdx.x * 4 + (threadIdx.x >> 6);
  const int head = lane >> 4;
  const int start = offs[n], end = offs[n + 1];
  const float ald_my = al[n * 8 + 4 + head];
  float ax = 0.f, ay = 0.f, az = 0.f, aw = 0.f, denom = 0.f;
  int i = start;
  const int e4 = start + ((end - start) & ~3);
  for (; i < e4; i += 4) {
    const int s0 = csr[i], s1 = csr[i + 1], s2 = csr[i + 2], s3 = csr[i + 3];
    union { ushort4 u; __half2 h2[2]; } c0, c1, c2, c3;
    c0.u = *(const ushort4*)(h + (size_t)s0 * 256 + lane * 4);
    c1.u = *(const ushort4*)(h + (size_t)s1 * 256 + lane * 4);
    c2.u = *(const ushort4*)(h + (size_t)s2 * 256 + lane * 4);
    c3.u = *(const ushort4*)(h + (size_t)s3 * 256 + lane * 4);
    const float p0 = __expf(lrelu(al[s0 * 8 + head] + ald_my));
    const float p1 = __expf(lrelu(al[s1 * 8 + head] + ald_my));
    const float p2 = __expf(lrelu(al[s2 * 8 + head] + ald_my));
    const float p3 = __expf(lrelu(al[s3 * 8 + head] + ald_my));
    denom += (p0 + p1) + (p2 + p3);
    float2 f;
    f = __half22float2(c0.h2[0]); ax = fmaf(p0, f.x, ax); ay = fmaf(p0, f.y, ay);
    f = __half22float2(c0.h2[1]); az = fmaf(p0, f.x, az); aw = fmaf(p0, f.y, aw);
    f = __half22float2(c1.h2[0]); ax = fmaf(p1, f.x, ax); ay = fmaf(p1, f.y, ay);
    f = __half22float2(c1.h2[1]); az = fmaf(p1, f.x, az); aw = fmaf(p1, f.y, aw);
    f = __half22float2(c2.h2[0]); ax = fmaf(p2, f.x, ax); ay = fmaf(p2, f.y, ay);
    f = __half22float2(c2.h2[1]); az = fmaf(p2, f.x, az); aw = fmaf(p2, f.y, aw);
    f = __half22float2(c3.h2[0]); ax = fmaf(p3, f.x, ax); ay = fmaf(p3, f.y, ay);
    f = __half22float2(c3.h2[1]); az = fmaf(p3, f.x, az); aw = fmaf(p3, f.y, aw);
  }
  for (; i < end; ++i) {
    const int s = csr[i];
    union { ushort4 u; __half2 h2[2]; } cv;
    cv.u = *(const ushort4*)(h + (size_t)s * 256 + lane * 4);
    const float p = __expf(lrelu(al[s * 8 + head] + ald_my));
    denom += p;
    float2 f;
    f = __half22float2(cv.h2[0]); ax = fmaf(p, f.x, ax); ay = fmaf(p, f.y, ay);
    f = __half22float2(cv.h2[1]); az = fmaf(p, f.x, az); aw = fmaf(p, f.y, aw);
  }
  const float inv = 0.25f / denom;  // alpha normalize + head mean
  ax *= inv; ay *= inv; az *= inv; aw *= inv;
  ax += __shfl_xor(ax, 16, 64); ax += __shfl_xor(ax, 32, 64);
  ay += __shfl_xor(ay, 16, 64); ay += __shfl_xor(ay, 32, 64);
  az += __shfl_xor(az, 16, 64); az += __shfl_xor(az, 32, 64);
  aw += __shfl_xor(aw, 16, 64); aw += __shfl_xor(aw, 32, 64);
  if (lane < 16) {
    const float4 b4 = *(const float4*)&bias[lane * 4];
    float4 o;
    o.x = ax + b4.x; o.y = ay + b4.y; o.z = az + b4.z; o.w = aw + b4.w;
    if (mode) {
      o.x = fmaxf(o.x, 0.f); o.y = fmaxf(o.y, 0.f);
      o.z = fmaxf(o.z, 0.f); o.w = fmaxf(o.w, 0.f);
      union { ushort4 u; __half2 h2[2]; } pk;
      pk.h2[0] = __floats2half2_rn(o.x, o.y);
      pk.h2[1] = __floats2half2_rn(o.z, o.w);
      *(ushort4*)(outh + (size_t)n * 64 + lane * 4) = pk.u;
    } else {
      *(float4*)&outf[n * 64 + lane * 4] = o;
    }
  }
}

// ---------------- node MLP heads (wave per node; no atomics) ----------------
__global__ void k_heads(const float* __restrict__ emb,
                        const float* __restrict__ aw1, const float* __restrict__ ab1,
                        const float* __restrict__ aw2, const float* __restrict__ ab2,
                        const float* __restrict__ rw1, const float* __restrict__ rb1,
                        const float* __restrict__ rw2, const float* __restrict__ rb2,
                        const float* __restrict__ cw1, const float* __restrict__ cb1,
                        const float* __restrict__ cw2, const float* __restrict__ cb2,
                        float* __restrict__ anomaly, float* __restrict__ risk,
                        float* __restrict__ resource) {
  const int lane = threadIdx.x & 63;
  const int n = blockIdx.x * 4 + (threadIdx.x >> 6);
  const float e = emb[n * 64 + lane];
  const int k = lane & 31;
  const bool hi = lane >= 32;
  const float* w1 = hi ? rw1 : aw1;
  const float* b1 = hi ? rb1 : ab1;
  float hA = b1[k];
  float hC = cb1[k];
  for (int cc = 0; cc < 64; ++cc) {
    float bc = __shfl(e, cc, 64);
    hA = fmaf(bc, w1[cc * 32 + k], hA);
    hC = fmaf(bc, cw1[cc * 32 + k], hC);
  }
  hA = fmaxf(hA, 0.f);
  hC = fmaxf(hC, 0.f);
  const float* w2 = hi ? rw2 : aw2;
  float pA = hA * w2[k];
  float pR[5];
#pragma unroll
  for (int j = 0; j < 5; ++j) pR[j] = hC * cw2[k * 5 + j];
#pragma unroll
  for (int off = 1; off <= 16; off <<= 1) {
    pA += __shfl_xor(pA, off, 64);
#pragma unroll
    for (int j = 0; j < 5; ++j) pR[j] += __shfl_xor(pR[j], off, 64);
  }
  if (lane == 0) {
    anomaly[n] = 1.f / (1.f + __expf(-(pA + ab2[0])));
#pragma unroll
    for (int j = 0; j < 5; ++j) resource[n * 5 + j] = pR[j] + cb2[j];
  }
  if (lane == 32) risk[n] = 1.f / (1.f + __expf(-(pA + rb2[0])));
}

// ---------------- pooling + graph MLP (1 block per graph; batch is SORTED) -------
__global__ void k_pool(const float* __restrict__ emb, const int* __restrict__ batch,
                       const float* __restrict__ gw1, const float* __restrict__ gb1,
                       const float* __restrict__ gw2, const float* __restrict__ gb2,
                       float* __restrict__ logits) {
  const int g = blockIdx.x;
  const int tid = threadIdx.x;
  const int c = tid & 63, w = tid >> 6;
  int lo = 0, hi = NN;
  while (lo < hi) { int mid = (lo + hi) >> 1; if (batch[mid] < g) lo = mid + 1; else hi = mid; }
  const int start = lo;
  hi = NN;
  while (lo < hi) { int mid = (lo + hi) >> 1; if (batch[mid] < g + 1) lo = mid + 1; else hi = mid; }
  const int end = lo;

  float s = 0.f;
  for (int n = start + w; n < end; n += 4) s += emb[n * 64 + c];
  __shared__ float sm[4][64];
  sm[w][c] = s;
  __syncthreads();
  __shared__ float prow[64];
  if (tid < 64) {
    float v = sm[0][tid] + sm[1][tid] + sm[2][tid] + sm[3][tid];
    prow[tid] = v * (1.f / fmaxf((float)(end - start), 1.f));
  }
  __syncthreads();
  if (tid < 32) {
    float hG = gb1[tid];
    for (int cc = 0; cc < 64; ++cc) hG = fmaf(prow[cc], gw1[cc * 32 + tid], hG);
    hG = fmaxf(hG, 0.f);
    float p[4];
#pragma unroll
    for (int j = 0; j < 4; ++j) p[j] = hG * gw2[tid * 4 + j];
#pragma unroll
    for (int off = 1; off <= 16; off <<= 1) {
#pragma unroll
      for (int j = 0; j < 4; ++j) p[j] += __shfl_xor(p[j], off, 64);
    }
    if (tid == 0) {
#pragma unroll
      for (int j = 0; j < 4; ++j) logits[g * 4 + j] = p[j] + gb2[j];
    }
  }
}

extern "C" void kernel_launch(void* const* d_in, const int* in_sizes, int n_in,
                              void* d_out, int out_size, void* d_ws, size_t ws_size,
                              hipStream_t stream) {
  const float* x = (const float*)d_in[0];
  const int* ei = (const int*)d_in[1];
  const int* batch = (const int*)d_in[2];
  const float* W1 = (const float*)d_in[3];
  const float* as1 = (const float*)d_in[4];
  const float* ad1 = (const float*)d_in[5];
  const float* b1 = (const float*)d_in[6];
  const float* W2 = (const float*)d_in[7];
  const float* as2 = (const float*)d_in[8];
  const float* ad2 = (const float*)d_in[9];
  const float* b2 = (const float*)d_in[10];
  const float* W3 = (const float*)d_in[11];
  const float* as3 = (const float*)d_in[12];
  const float* ad3 = (const float*)d_in[13];
  const float* b3 = (const float*)d_in[14];
  const float* aw1 = (const float*)d_in[15];
  const float* ab1 = (const float*)d_in[16];
  const float* aw2 = (const float*)d_in[17];
  const float* ab2 = (const float*)d_in[18];
  const float* rw1 = (const float*)d_in[19];
  const float* rb1 = (const float*)d_in[20];
  const float* rw2 = (const float*)d_in[21];
  const float* rb2 = (const float*)d_in[22];
  const float* cw1 = (const float*)d_in[23];
  const float* cb1 = (const float*)d_in[24];
  const float* cw2 = (const float*)d_in[25];
  const float* cb2 = (const float*)d_in[26];
  const float* gw1 = (const float*)d_in[27];
  const float* gb1 = (const float*)d_in[28];
  const float* gw2 = (const float*)d_in[29];
  const float* gb2 = (const float*)d_in[30];

  float* out = (float*)d_out;
  float* emb = out;                       // [N,64]
  float* anomaly = out + NN * 64;         // [N]
  float* risk = anomaly + NN;             // [N]
  float* resource = risk + NN;            // [N,5]
  float* logits = resource + NN * 5;      // [G,4]

  char* ws = (char*)d_ws;
  int* deg = (int*)ws;            ws += (size_t)NN * 4;
  int* cursor = (int*)ws;         ws += (size_t)NN * 4;
  size_t zbytes = (size_t)(NN * 2) * 4;
  int* offs = (int*)ws;           ws += (size_t)(NN + 4) * 4;
  int* csum = (int*)ws;           ws += 256 * 4;
  int* cbase = (int*)ws;          ws += 256 * 4;
  int* csr = (int*)ws;            ws += (size_t)ET * 4;
  __half* h = (__half*)ws;        ws += (size_t)NN * 256 * 2;
  float* al = (float*)ws;         ws += (size_t)NN * 8 * 4;
  __half* xh1 = (__half*)ws;      ws += (size_t)NN * 128 * 2;
  __half* xh64 = (__half*)ws;     ws += (size_t)NN * 64 * 2;

  hipMemsetAsync(d_ws, 0, zbytes, stream);
  k_count<<<(ET + 255) / 256, 256, 0, stream>>>(ei, deg);
  k_scan1<<<NCH, 256, 0, stream>>>(deg, csum);
  k_scan2<<<1, 256, 0, stream>>>(csum, cbase, offs);
  k_scan3<<<NCH, 256, 0, stream>>>(deg, cbase, offs);
  k_fill<<<(ET + 255) / 256, 256, 0, stream>>>(ei, offs, cursor, csr);

  k_cvt<<<(NN * 128 / 4 + 255) / 256, 256, 0, stream>>>(x, (__half2*)xh1, NN * 128 / 4);

  // layer 1
  k_mm<128><<<512, 256, 0, stream>>>(xh1, W1, h);
  k_al<<<NN / 4, 256, 0, stream>>>(h, as1, ad1, al);
  k_agg<<<NN / 4, 256, 0, stream>>>(h, al, offs, csr, b1, nullptr, xh64, 1);
  // layer 2
  k_mm<64><<<512, 256, 0, stream>>>(xh64, W2, h);
  k_al<<<NN / 4, 256, 0, stream>>>(h, as2, ad2, al);
  k_agg<<<NN / 4, 256, 0, stream>>>(h, al, offs, csr, b2, nullptr, xh64, 1);
  // layer 3
  k_mm<64><<<512, 256, 0, stream>>>(xh64, W3, h);
  k_al<<<NN / 4, 256, 0, stream>>>(h, as3, ad3, al);
  k_agg<<<NN / 4, 256, 0, stream>>>(h, al, offs, csr, b3, emb, nullptr, 0);

  k_heads<<<NN / 4, 256, 0, stream>>>(emb, aw1, ab1, aw2, ab2, rw1, rb1, rw2, rb2,
                                      cw1, cb1, cw2, cb2, anomaly, risk, resource);
  k_pool<<<GG, 256, 0, stream>>>(emb, batch, gw1, gb1, gw2, gb2, logits);
}

// Round 6
// 618.670 us; speedup vs baseline: 2.1179x; 1.0315x over previous
//
#include <hip/hip_runtime.h>
#include <hip/hip_fp16.h>
#include <math.h>

#define NN 50000
#define EE 800000
#define ET (NN + EE)   // 850000 edges incl. self-loops
#define GG 64
#define NCH ((NN + 255) / 256)   // 196 chunks for the hierarchical scan

typedef _Float16 f16x8 __attribute__((ext_vector_type(8)));
typedef float f32x4 __attribute__((ext_vector_type(4)));

__device__ __forceinline__ float lrelu(float x) { return x > 0.f ? x : 0.2f * x; }

// ---------------- CSR build (self-loops handled analytically) ----------------
__global__ void k_count(const int* __restrict__ ei, int* __restrict__ deg) {
  int e = blockIdx.x * 256 + threadIdx.x;
  if (e >= EE) return;
  atomicAdd(&deg[ei[EE + e]], 1);
}

// scan of (deg[i]+1): +1 is the self-loop
__global__ void k_scan1(const int* __restrict__ deg, int* __restrict__ csum) {
  const int i = blockIdx.x * 256 + threadIdx.x;
  int v = (i < NN) ? deg[i] + 1 : 0;
#pragma unroll
  for (int off = 32; off >= 1; off >>= 1) v += __shfl_xor(v, off, 64);
  __shared__ int sm[4];
  if ((threadIdx.x & 63) == 0) sm[threadIdx.x >> 6] = v;
  __syncthreads();
  if (threadIdx.x == 0) csum[blockIdx.x] = sm[0] + sm[1] + sm[2] + sm[3];
}

__global__ void k_scan2(const int* __restrict__ csum, int* __restrict__ cbase,
                        int* __restrict__ offs) {
  __shared__ int s[256];
  const int t = threadIdx.x;
  int v = (t < NCH) ? csum[t] : 0;
  s[t] = v;
  __syncthreads();
  for (int off = 1; off < 256; off <<= 1) {
    int u = (t >= off) ? s[t - off] : 0;
    __syncthreads();
    s[t] += u;
    __syncthreads();
  }
  cbase[t] = s[t] - v;
  if (t == 255) offs[NN] = s[255];
}

// also writes the self-loop entry csr[offs[i]] = i
__global__ void k_scan3(const int* __restrict__ deg, const int* __restrict__ cbase,
                        int* __restrict__ offs, int* __restrict__ csr) {
  __shared__ int s[256];
  const int t = threadIdx.x;
  const int i = blockIdx.x * 256 + t;
  int v = (i < NN) ? deg[i] + 1 : 0;
  s[t] = v;
  __syncthreads();
  for (int off = 1; off < 256; off <<= 1) {
    int u = (t >= off) ? s[t - off] : 0;
    __syncthreads();
    s[t] += u;
    __syncthreads();
  }
  if (i < NN) {
    const int o = cbase[blockIdx.x] + s[t] - v;
    offs[i] = o;
    csr[o] = i;        // self-loop at slot 0 of the bucket
  }
}

__global__ void k_fill(const int* __restrict__ ei, const int* __restrict__ offs,
                       int* __restrict__ cursor, int* __restrict__ csr) {
  int e = blockIdx.x * 256 + threadIdx.x;
  if (e >= EE) return;
  const int src = ei[e], dst = ei[EE + e];
  const int slot = offs[dst] + 1 + atomicAdd(&cursor[dst], 1);
  csr[slot] = src;
}

// ---------------- x fp32 -> fp16 ----------------
__global__ void k_cvt(const float* __restrict__ x, __half2* __restrict__ xh, int n4) {
  int i = blockIdx.x * 256 + threadIdx.x;
  if (i >= n4) return;
  float4 v = ((const float4*)x)[i];
  xh[i * 2] = __floats2half2_rn(v.x, v.y);
  xh[i * 2 + 1] = __floats2half2_rn(v.z, v.w);
}

// ---------------- h = x@W via MFMA 16x16x32 f16, al_s/al_d fused ----------------
// Block = 4 waves; wave wv owns cols [64wv,64wv+64) == head wv.
// A frag: lane holds A[m=lane&15][k=quad*8+j]; C/D: D[row=quad*4+r][col=lane&15].
// al reduce: per quad, rows quad*4+r; sum over nn lanes (shfl_xor 1,2,4,8).
template <int K>
__global__ __launch_bounds__(256) void k_mm(const __half* __restrict__ xh,
                                            const float* __restrict__ W,
                                            const float* __restrict__ a_s,
                                            const float* __restrict__ a_d,
                                            __half* __restrict__ h,
                                            float* __restrict__ al) {
  constexpr int KC = K / 32;
  const int lane = threadIdx.x & 63;
  const int wv = threadIdx.x >> 6;
  const int quad = lane >> 4, nn = lane & 15;
  f16x8 bf[KC][4];
  float asf[4], adf[4];
#pragma unroll
  for (int ct = 0; ct < 4; ++ct) {
    const int col = wv * 64 + ct * 16 + nn;
#pragma unroll
    for (int kc = 0; kc < KC; ++kc)
#pragma unroll
      for (int j = 0; j < 8; ++j)
        bf[kc][ct][j] = (_Float16)W[(kc * 32 + quad * 8 + j) * 256 + col];
    asf[ct] = a_s[wv * 64 + ct * 16 + nn];
    adf[ct] = a_d[wv * 64 + ct * 16 + nn];
  }
  for (int rt = blockIdx.x; rt < NN / 16; rt += gridDim.x) {
    const int row0 = rt * 16;
    const _Float16* xrow = (const _Float16*)xh + (size_t)(row0 + nn) * K + quad * 8;
    f16x8 af[KC];
#pragma unroll
    for (int kc = 0; kc < KC; ++kc) af[kc] = *(const f16x8*)(xrow + kc * 32);
    f32x4 accv[4];
#pragma unroll
    for (int ct = 0; ct < 4; ++ct) {
      f32x4 acc = {0.f, 0.f, 0.f, 0.f};
#pragma unroll
      for (int kc = 0; kc < KC; ++kc)
        acc = __builtin_amdgcn_mfma_f32_16x16x32_f16(af[kc], bf[kc][ct], acc, 0, 0, 0);
      accv[ct] = acc;
      const int col = wv * 64 + ct * 16 + nn;
#pragma unroll
      for (int r = 0; r < 4; ++r)
        h[(size_t)(row0 + quad * 4 + r) * 256 + col] = __float2half(acc[r]);
    }
    // fused al: row (quad*4+r) partial = sum_ct accv[ct][r]*asf[ct], reduce over nn
    float sa[4] = {0.f, 0.f, 0.f, 0.f}, sd[4] = {0.f, 0.f, 0.f, 0.f};
#pragma unroll
    for (int ct = 0; ct < 4; ++ct)
#pragma unroll
      for (int r = 0; r < 4; ++r) {
        sa[r] = fmaf(accv[ct][r], asf[ct], sa[r]);
        sd[r] = fmaf(accv[ct][r], adf[ct], sd[r]);
      }
#pragma unroll
    for (int off = 1; off <= 8; off <<= 1)
#pragma unroll
      for (int r = 0; r < 4; ++r) {
        sa[r] += __shfl_xor(sa[r], off, 64);
        sd[r] += __shfl_xor(sd[r], off, 64);
      }
    if (nn == 0) {
#pragma unroll
      for (int r = 0; r < 4; ++r) {
        al[(size_t)(row0 + quad * 4 + r) * 8 + wv] = sa[r];
        al[(size_t)(row0 + quad * 4 + r) * 8 + 4 + wv] = sd[r];
      }
    }
  }
}

// ---------------- per-dst softmax + aggregate (2 nodes/wave, 16B/lane) --------
// 32-lane half owns one node; lane covers 8 fp16 channels (head = l32>>3).
// mode 1: relu + fp16 store to outh. mode 0: fp32 store to outf.
__global__ void k_agg(const __half* __restrict__ h, const float* __restrict__ al,
                      const int* __restrict__ offs, const int* __restrict__ csr,
                      const float* __restrict__ bias, float* __restrict__ outf,
                      __half* __restrict__ outh, const int mode) {
  const int tid = threadIdx.x;
  const int l32 = tid & 31;
  const int n = blockIdx.x * 8 + (tid >> 5);
  const int head = l32 >> 3;
  const int start = offs[n], end = offs[n + 1];
  const float ald_my = al[n * 8 + 4 + head];
  const __half* hbase = h + (size_t)l32 * 8;
  float acc[8] = {};
  float denom = 0.f;
  union U { int4 v; __half2 h2[4]; };
  int i = start;
  const int e4 = start + ((end - start) & ~3);
  for (; i < e4; i += 4) {
    const int s0 = csr[i], s1 = csr[i + 1], s2 = csr[i + 2], s3 = csr[i + 3];
    U c0, c1, c2, c3;
    c0.v = *(const int4*)(hbase + (size_t)s0 * 256);
    c1.v = *(const int4*)(hbase + (size_t)s1 * 256);
    c2.v = *(const int4*)(hbase + (size_t)s2 * 256);
    c3.v = *(const int4*)(hbase + (size_t)s3 * 256);
    const float p0 = __expf(lrelu(al[s0 * 8 + head] + ald_my));
    const float p1 = __expf(lrelu(al[s1 * 8 + head] + ald_my));
    const float p2 = __expf(lrelu(al[s2 * 8 + head] + ald_my));
    const float p3 = __expf(lrelu(al[s3 * 8 + head] + ald_my));
    denom += (p0 + p1) + (p2 + p3);
    float2 f;
#pragma unroll
    for (int j = 0; j < 4; ++j) {
      f = __half22float2(c0.h2[j]);
      acc[2 * j] = fmaf(p0, f.x, acc[2 * j]); acc[2 * j + 1] = fmaf(p0, f.y, acc[2 * j + 1]);
    }
#pragma unroll
    for (int j = 0; j < 4; ++j) {
      f = __half22float2(c1.h2[j]);
      acc[2 * j] = fmaf(p1, f.x, acc[2 * j]); acc[2 * j + 1] = fmaf(p1, f.y, acc[2 * j + 1]);
    }
#pragma unroll
    for (int j = 0; j < 4; ++j) {
      f = __half22float2(c2.h2[j]);
      acc[2 * j] = fmaf(p2, f.x, acc[2 * j]); acc[2 * j + 1] = fmaf(p2, f.y, acc[2 * j + 1]);
    }
#pragma unroll
    for (int j = 0; j < 4; ++j) {
      f = __half22float2(c3.h2[j]);
      acc[2 * j] = fmaf(p3, f.x, acc[2 * j]); acc[2 * j + 1] = fmaf(p3, f.y, acc[2 * j + 1]);
    }
  }
  for (; i < end; ++i) {
    const int s = csr[i];
    U cv;
    cv.v = *(const int4*)(hbase + (size_t)s * 256);
    const float p = __expf(lrelu(al[s * 8 + head] + ald_my));
    denom += p;
    float2 f;
#pragma unroll
    for (int j = 0; j < 4; ++j) {
      f = __half22float2(cv.h2[j]);
      acc[2 * j] = fmaf(p, f.x, acc[2 * j]); acc[2 * j + 1] = fmaf(p, f.y, acc[2 * j + 1]);
    }
  }
  const float inv = 0.25f / denom;  // per-head alpha normalize + head mean
#pragma unroll
  for (int j = 0; j < 8; ++j) acc[j] *= inv;
  // sum across the 4 heads (lanes with same l32&7): xor 8, 16 stay in the half
#pragma unroll
  for (int j = 0; j < 8; ++j) acc[j] += __shfl_xor(acc[j], 8, 64);
#pragma unroll
  for (int j = 0; j < 8; ++j) acc[j] += __shfl_xor(acc[j], 16, 64);
  if (l32 < 8) {
    const float4 b0 = *(const float4*)&bias[l32 * 8];
    const float4 b1 = *(const float4*)&bias[l32 * 8 + 4];
    float o[8];
    o[0] = acc[0] + b0.x; o[1] = acc[1] + b0.y; o[2] = acc[2] + b0.z; o[3] = acc[3] + b0.w;
    o[4] = acc[4] + b1.x; o[5] = acc[5] + b1.y; o[6] = acc[6] + b1.z; o[7] = acc[7] + b1.w;
    if (mode) {
      union U2 { int4 v; __half2 h2[4]; } pk;
#pragma unroll
      for (int j = 0; j < 4; ++j)
        pk.h2[j] = __floats2half2_rn(fmaxf(o[2 * j], 0.f), fmaxf(o[2 * j + 1], 0.f));
      *(int4*)(outh + (size_t)n * 64 + l32 * 8) = pk.v;
    } else {
      float4 v0 = {o[0], o[1], o[2], o[3]}, v1 = {o[4], o[5], o[6], o[7]};
      *(float4*)&outf[n * 64 + l32 * 8] = v0;
      *(float4*)&outf[n * 64 + l32 * 8 + 4] = v1;
    }
  }
}

// ---------------- node MLP heads (wave per node; no atomics) ----------------
__global__ void k_heads(const float* __restrict__ emb,
                        const float* __restrict__ aw1, const float* __restrict__ ab1,
                        const float* __restrict__ aw2, const float* __restrict__ ab2,
                        const float* __restrict__ rw1, const float* __restrict__ rb1,
                        const float* __restrict__ rw2, const float* __restrict__ rb2,
                        const float* __restrict__ cw1, const float* __restrict__ cb1,
                        const float* __restrict__ cw2, const float* __restrict__ cb2,
                        float* __restrict__ anomaly, float* __restrict__ risk,
                        float* __restrict__ resource) {
  const int lane = threadIdx.x & 63;
  const int n = blockIdx.x * 4 + (threadIdx.x >> 6);
  const float e = emb[n * 64 + lane];
  const int k = lane & 31;
  const bool hi = lane >= 32;
  const float* w1 = hi ? rw1 : aw1;
  const float* b1 = hi ? rb1 : ab1;
  float hA = b1[k];
  float hC = cb1[k];
  for (int cc = 0; cc < 64; ++cc) {
    float bc = __shfl(e, cc, 64);
    hA = fmaf(bc, w1[cc * 32 + k], hA);
    hC = fmaf(bc, cw1[cc * 32 + k], hC);
  }
  hA = fmaxf(hA, 0.f);
  hC = fmaxf(hC, 0.f);
  const float* w2 = hi ? rw2 : aw2;
  float pA = hA * w2[k];
  float pR[5];
#pragma unroll
  for (int j = 0; j < 5; ++j) pR[j] = hC * cw2[k * 5 + j];
#pragma unroll
  for (int off = 1; off <= 16; off <<= 1) {
    pA += __shfl_xor(pA, off, 64);
#pragma unroll
    for (int j = 0; j < 5; ++j) pR[j] += __shfl_xor(pR[j], off, 64);
  }
  if (lane == 0) {
    anomaly[n] = 1.f / (1.f + __expf(-(pA + ab2[0])));
#pragma unroll
    for (int j = 0; j < 5; ++j) resource[n * 5 + j] = pR[j] + cb2[j];
  }
  if (lane == 32) risk[n] = 1.f / (1.f + __expf(-(pA + rb2[0])));
}

// ---------------- pooling + graph MLP (1 block per graph; batch is SORTED) -------
__global__ void k_pool(const float* __restrict__ emb, const int* __restrict__ batch,
                       const float* __restrict__ gw1, const float* __restrict__ gb1,
                       const float* __restrict__ gw2, const float* __restrict__ gb2,
                       float* __restrict__ logits) {
  const int g = blockIdx.x;
  const int tid = threadIdx.x;
  const int c = tid & 63, w = tid >> 6;
  int lo = 0, hi = NN;
  while (lo < hi) { int mid = (lo + hi) >> 1; if (batch[mid] < g) lo = mid + 1; else hi = mid; }
  const int start = lo;
  hi = NN;
  while (lo < hi) { int mid = (lo + hi) >> 1; if (batch[mid] < g + 1) lo = mid + 1; else hi = mid; }
  const int end = lo;

  float s = 0.f;
  for (int n = start + w; n < end; n += 4) s += emb[n * 64 + c];
  __shared__ float sm[4][64];
  sm[w][c] = s;
  __syncthreads();
  __shared__ float prow[64];
  if (tid < 64) {
    float v = sm[0][tid] + sm[1][tid] + sm[2][tid] + sm[3][tid];
    prow[tid] = v * (1.f / fmaxf((float)(end - start), 1.f));
  }
  __syncthreads();
  if (tid < 32) {
    float hG = gb1[tid];
    for (int cc = 0; cc < 64; ++cc) hG = fmaf(prow[cc], gw1[cc * 32 + tid], hG);
    hG = fmaxf(hG, 0.f);
    float p[4];
#pragma unroll
    for (int j = 0; j < 4; ++j) p[j] = hG * gw2[tid * 4 + j];
#pragma unroll
    for (int off = 1; off <= 16; off <<= 1) {
#pragma unroll
      for (int j = 0; j < 4; ++j) p[j] += __shfl_xor(p[j], off, 64);
    }
    if (tid == 0) {
#pragma unroll
      for (int j = 0; j < 4; ++j) logits[g * 4 + j] = p[j] + gb2[j];
    }
  }
}

extern "C" void kernel_launch(void* const* d_in, const int* in_sizes, int n_in,
                              void* d_out, int out_size, void* d_ws, size_t ws_size,
                              hipStream_t stream) {
  const float* x = (const float*)d_in[0];
  const int* ei = (const int*)d_in[1];
  const int* batch = (const int*)d_in[2];
  const float* W1 = (const float*)d_in[3];
  const float* as1 = (const float*)d_in[4];
  const float* ad1 = (const float*)d_in[5];
  const float* b1 = (const float*)d_in[6];
  const float* W2 = (const float*)d_in[7];
  const float* as2 = (const float*)d_in[8];
  const float* ad2 = (const float*)d_in[9];
  const float* b2 = (const float*)d_in[10];
  const float* W3 = (const float*)d_in[11];
  const float* as3 = (const float*)d_in[12];
  const float* ad3 = (const float*)d_in[13];
  const float* b3 = (const float*)d_in[14];
  const float* aw1 = (const float*)d_in[15];
  const float* ab1 = (const float*)d_in[16];
  const float* aw2 = (const float*)d_in[17];
  const float* ab2 = (const float*)d_in[18];
  const float* rw1 = (const float*)d_in[19];
  const float* rb1 = (const float*)d_in[20];
  const float* rw2 = (const float*)d_in[21];
  const float* rb2 = (const float*)d_in[22];
  const float* cw1 = (const float*)d_in[23];
  const float* cb1 = (const float*)d_in[24];
  const float* cw2 = (const float*)d_in[25];
  const float* cb2 = (const float*)d_in[26];
  const float* gw1 = (const float*)d_in[27];
  const float* gb1 = (const float*)d_in[28];
  const float* gw2 = (const float*)d_in[29];
  const float* gb2 = (const float*)d_in[30];

  float* out = (float*)d_out;
  float* emb = out;                       // [N,64]
  float* anomaly = out + NN * 64;         // [N]
  float* risk = anomaly + NN;             // [N]
  float* resource = risk + NN;            // [N,5]
  float* logits = resource + NN * 5;      // [G,4]

  char* ws = (char*)d_ws;
  int* deg = (int*)ws;            ws += (size_t)NN * 4;
  int* cursor = (int*)ws;         ws += (size_t)NN * 4;
  size_t zbytes = (size_t)(NN * 2) * 4;
  int* offs = (int*)ws;           ws += (size_t)(NN + 4) * 4;
  int* csum = (int*)ws;           ws += 256 * 4;
  int* cbase = (int*)ws;          ws += 256 * 4;
  int* csr = (int*)ws;            ws += (size_t)ET * 4;
  __half* h = (__half*)ws;        ws += (size_t)NN * 256 * 2;
  float* al = (float*)ws;         ws += (size_t)NN * 8 * 4;
  __half* xh1 = (__half*)ws;      ws += (size_t)NN * 128 * 2;
  __half* xh64 = (__half*)ws;     ws += (size_t)NN * 64 * 2;

  hipMemsetAsync(d_ws, 0, zbytes, stream);
  k_count<<<(EE + 255) / 256, 256, 0, stream>>>(ei, deg);
  k_scan1<<<NCH, 256, 0, stream>>>(deg, csum);
  k_scan2<<<1, 256, 0, stream>>>(csum, cbase, offs);
  k_scan3<<<NCH, 256, 0, stream>>>(deg, cbase, offs, csr);
  k_fill<<<(EE + 255) / 256, 256, 0, stream>>>(ei, offs, cursor, csr);

  k_cvt<<<(NN * 128 / 4 + 255) / 256, 256, 0, stream>>>(x, (__half2*)xh1, NN * 128 / 4);

  // layer 1
  k_mm<128><<<512, 256, 0, stream>>>(xh1, W1, as1, ad1, h, al);
  k_agg<<<NN / 8, 256, 0, stream>>>(h, al, offs, csr, b1, nullptr, xh64, 1);
  // layer 2
  k_mm<64><<<512, 256, 0, stream>>>(xh64, W2, as2, ad2, h, al);
  k_agg<<<NN / 8, 256, 0, stream>>>(h, al, offs, csr, b2, nullptr, xh64, 1);
  // layer 3
  k_mm<64><<<512, 256, 0, stream>>>(xh64, W3, as3, ad3, h, al);
  k_agg<<<NN / 8, 256, 0, stream>>>(h, al, offs, csr, b3, emb, nullptr, 0);

  k_heads<<<NN / 4, 256, 0, stream>>>(emb, aw1, ab1, aw2, ab2, rw1, rb1, rw2, rb2,
                                      cw1, cb1, cw2, cb2, anomaly, risk, resource);
  k_pool<<<GG, 256, 0, stream>>>(emb, batch, gw1, gb1, gw2, gb2, logits);
}